// Round 1
// baseline (23782.872 us; speedup 1.0000x reference)
//
#include <hip/hip_runtime.h>
#include <math.h>

#define TT     4000
#define DENC   1024
#define HD     1024
#define DEMB   512
#define VD     8193
#define NPH    800
#define BLANK  8192
#define NWG    256
#define NTHR   512
#define SPEC   128

// ---- workspace float offsets (barrier occupies first 256 bytes) ----
#define WS_BAR_BYTES 256
#define WSF_H     64
#define WSF_C     (WSF_H + 1024)
#define WSF_G     (WSF_C + 1024)            // 2*4096 gate double buffer
#define WSF_PRED  (WSF_G + 8192)            // SPEC*1024
#define WSF_H2    (WSF_PRED + SPEC*1024)
#define WSF_C2    (WSF_H2 + SPEC*1024)
#define WSF_AMAX  (WSF_C2 + SPEC*1024)      // SPEC ints

// ---- LDS layout (floats) ----
#define S_WG   0        // [16][1536]
#define S_WP   24576    // [4][1024]
#define S_XH   28672    // [1536]  (x:0..511, h:512..1535)
#define S_CL   30208    // [1024]
#define SMEM_FLOATS 31232
#define SMEM_BYTES (SMEM_FLOATS * 4)
// GEMM reuses: Wt at 0 ([16][132]), Xt at 2112 ([16][68])

struct Ctx {
  const float *enc, *emb, *Wih, *Whh, *bl, *Wpred, *bp, *Wjoin, *bj;
  const int* phon;
  float *h, *c, *gates, *preds, *h2s, *c2s;
  int* amax;
  unsigned* bar;
  float *out_align, *out_pred, *out_valid;
};

__device__ __forceinline__ void grid_barrier(unsigned* bar) {
  __syncthreads();
  if (threadIdx.x == 0) {
    __threadfence();
    unsigned g = __hip_atomic_load(&bar[1], __ATOMIC_RELAXED, __HIP_MEMORY_SCOPE_AGENT);
    unsigned v = __hip_atomic_fetch_add(&bar[0], 1u, __ATOMIC_RELAXED, __HIP_MEMORY_SCOPE_AGENT);
    if (v == (unsigned)(NWG - 1)) {
      __hip_atomic_store(&bar[0], 0u, __ATOMIC_RELAXED, __HIP_MEMORY_SCOPE_AGENT);
      __hip_atomic_store(&bar[1], g + 1u, __ATOMIC_RELEASE, __HIP_MEMORY_SCOPE_AGENT);
    } else {
      while (__hip_atomic_load(&bar[1], __ATOMIC_RELAXED, __HIP_MEMORY_SCOPE_AGENT) == g)
        __builtin_amdgcn_s_sleep(1);
    }
    __threadfence();
  }
  __syncthreads();
}

// Speculative LSTM chain: K steps, token j = (j==0 ? tok0 : phon[tp+j-1]).
// Per step: distributed gates -> grid barrier -> redundant pointwise -> pred rows.
__device__ void chain_phase(const Ctx& C, float* sm, bool warm, int tok0, int K, int tp) {
  float* Wg = sm + S_WG;
  float* Wp = sm + S_WP;
  float* xh = sm + S_XH;
  float* cl = sm + S_CL;
  const int wid = threadIdx.x >> 6, lane = threadIdx.x & 63;
  const int g0 = blockIdx.x * 16, p0 = blockIdx.x * 4;

  // stage weight slices into LDS (float4)
  for (int rr = 0; rr < 2; ++rr) {
    int r = wid * 2 + rr;
    const float4* s4 = (const float4*)(C.Wih + (size_t)(g0 + r) * DEMB);
    float4* d4 = (float4*)(Wg + r * 1536);
    #pragma unroll
    for (int i = 0; i < 2; ++i) d4[lane + 64 * i] = s4[lane + 64 * i];
    const float4* s4h = (const float4*)(C.Whh + (size_t)(g0 + r) * HD);
    float4* d4h = (float4*)(Wg + r * 1536 + DEMB);
    #pragma unroll
    for (int i = 0; i < 4; ++i) d4h[lane + 64 * i] = s4h[lane + 64 * i];
  }
  if (wid < 4) {
    const float4* s4 = (const float4*)(C.Wpred + (size_t)(p0 + wid) * HD);
    float4* d4 = (float4*)(Wp + wid * 1024);
    #pragma unroll
    for (int i = 0; i < 4; ++i) d4[lane + 64 * i] = s4[lane + 64 * i];
  }
  for (int i = threadIdx.x; i < 1024; i += NTHR) {
    xh[512 + i] = warm ? 0.f : C.h[i];
    cl[i]       = warm ? 0.f : C.c[i];
  }

  for (int j = 0; j < K; ++j) {
    int tok = (j == 0) ? tok0 : C.phon[tp + j - 1];
    const float* xr = C.emb + (size_t)tok * DEMB;
    for (int i = threadIdx.x; i < DEMB; i += NTHR) xh[i] = xr[i];
    __syncthreads();

    float* gb = C.gates + (size_t)(j & 1) * 4096;
    for (int rr = 0; rr < 2; ++rr) {
      int r = wid * 2 + rr;
      const float* wr = Wg + r * 1536;
      float s = 0.f;
      #pragma unroll
      for (int i = 0; i < 24; ++i) s = fmaf(wr[lane + 64 * i], xh[lane + 64 * i], s);
      #pragma unroll
      for (int m = 32; m; m >>= 1) s += __shfl_xor(s, m, 64);
      if (lane == 0) gb[g0 + r] = s + C.bl[g0 + r];
    }
    grid_barrier(C.bar);

    // redundant pointwise: every WG keeps full h,c locally
    for (int cell = threadIdx.x; cell < 1024; cell += NTHR) {
      float gi = gb[cell], gf = gb[cell + 1024], gg = gb[cell + 2048], go = gb[cell + 3072];
      float si = 1.f / (1.f + expf(-gi));
      float sf = 1.f / (1.f + expf(-gf));
      float so = 1.f / (1.f + expf(-go));
      float c2 = sf * cl[cell] + si * tanhf(gg);
      float h2 = so * tanhf(c2);
      cl[cell] = c2;
      xh[512 + cell] = h2;
      if (blockIdx.x == 0) { C.h2s[(size_t)j * 1024 + cell] = h2; C.c2s[(size_t)j * 1024 + cell] = c2; }
    }
    __syncthreads();

    if (wid < 4) {
      const float* wr = Wp + wid * 1024;
      float s = 0.f;
      #pragma unroll
      for (int i = 0; i < 16; ++i) s = fmaf(wr[lane + 64 * i], xh[512 + lane + 64 * i], s);
      #pragma unroll
      for (int m = 32; m; m >>= 1) s += __shfl_xor(s, m, 64);
      if (lane == 0) C.preds[(size_t)j * 1024 + p0 + wid] = s + C.bp[p0 + wid];
    }
    // no extra sync needed: pred reads xh[512..], next x-stage writes xh[0..511]
  }
}

// logits[t0+j][v] = b_join[v] + sum_k W_join[v][k]*relu(enc[t0+j][k]+pred[k]); written to out_align
__device__ void joiner_gemm(const Ctx& C, float* sm, int t0, int K, bool head) {
  float* Wt = sm;          // [16][132]
  float* Xt = sm + 2112;   // [16][68]
  const int tx = threadIdx.x & 31, ty = threadIdx.x >> 5;
  int jt_n = (K + 63) >> 6;
  int ntiles = jt_n * 65;
  for (int tile = blockIdx.x; tile < ntiles; tile += NWG) {
    int vt = tile % 65, jt = tile / 65;
    int v0 = vt * 128, j0 = jt * 64;
    float acc[4][4];
    #pragma unroll
    for (int a = 0; a < 4; ++a)
      #pragma unroll
      for (int b = 0; b < 4; ++b) acc[a][b] = 0.f;

    for (int kk = 0; kk < 1024; kk += 16) {
      {
        int r = threadIdx.x >> 2, seg = threadIdx.x & 3;
        int v = v0 + r;
        float4 w = make_float4(0.f, 0.f, 0.f, 0.f);
        if (v < VD) w = ((const float4*)(C.Wjoin + (size_t)v * 1024 + kk))[seg];
        Wt[(seg * 4 + 0) * 132 + r] = w.x;
        Wt[(seg * 4 + 1) * 132 + r] = w.y;
        Wt[(seg * 4 + 2) * 132 + r] = w.z;
        Wt[(seg * 4 + 3) * 132 + r] = w.w;
      }
      if (threadIdx.x < 256) {
        int r = threadIdx.x >> 2, seg = threadIdx.x & 3;
        int j = j0 + r;
        float4 xv = make_float4(0.f, 0.f, 0.f, 0.f);
        if (j < K) {
          float4 e = ((const float4*)(C.enc + (size_t)(t0 + j) * DENC + kk))[seg];
          const float* pr = C.preds + (head ? (size_t)j * 1024 : (size_t)0);
          float4 p = ((const float4*)(pr + kk))[seg];
          xv.x = fmaxf(e.x + p.x, 0.f);
          xv.y = fmaxf(e.y + p.y, 0.f);
          xv.z = fmaxf(e.z + p.z, 0.f);
          xv.w = fmaxf(e.w + p.w, 0.f);
        }
        Xt[(seg * 4 + 0) * 68 + r] = xv.x;
        Xt[(seg * 4 + 1) * 68 + r] = xv.y;
        Xt[(seg * 4 + 2) * 68 + r] = xv.z;
        Xt[(seg * 4 + 3) * 68 + r] = xv.w;
      }
      __syncthreads();
      #pragma unroll
      for (int k = 0; k < 16; ++k) {
        float4 a = *(const float4*)(Wt + k * 132 + (tx << 2));
        float4 b = *(const float4*)(Xt + k * 68 + (ty << 2));
        acc[0][0] = fmaf(a.x, b.x, acc[0][0]);
        acc[1][0] = fmaf(a.y, b.x, acc[1][0]);
        acc[2][0] = fmaf(a.z, b.x, acc[2][0]);
        acc[3][0] = fmaf(a.w, b.x, acc[3][0]);
        acc[0][1] = fmaf(a.x, b.y, acc[0][1]);
        acc[1][1] = fmaf(a.y, b.y, acc[1][1]);
        acc[2][1] = fmaf(a.z, b.y, acc[2][1]);
        acc[3][1] = fmaf(a.w, b.y, acc[3][1]);
        acc[0][2] = fmaf(a.x, b.z, acc[0][2]);
        acc[1][2] = fmaf(a.y, b.z, acc[1][2]);
        acc[2][2] = fmaf(a.z, b.z, acc[2][2]);
        acc[3][2] = fmaf(a.w, b.z, acc[3][2]);
        acc[0][3] = fmaf(a.x, b.w, acc[0][3]);
        acc[1][3] = fmaf(a.y, b.w, acc[1][3]);
        acc[2][3] = fmaf(a.z, b.w, acc[2][3]);
        acc[3][3] = fmaf(a.w, b.w, acc[3][3]);
      }
      __syncthreads();
    }
    int vb = v0 + (tx << 2), jb0 = j0 + (ty << 2);
    #pragma unroll
    for (int jj = 0; jj < 4; ++jj) {
      int j = jb0 + jj;
      if (j >= K) continue;
      size_t ro = (size_t)(t0 + j) * VD;
      #pragma unroll
      for (int q = 0; q < 4; ++q) {
        int v = vb + q;
        if (v < VD) C.out_align[ro + v] = acc[q][jj] + C.bj[v];
      }
    }
  }
}

// per-row max/argmax + logsumexp; logp in place
__device__ void reduce_phase(const Ctx& C, float* sm, int t0, int K, bool store_amax) {
  const int wid = threadIdx.x >> 6, lane = threadIdx.x & 63;
  float* rm = sm;              // 8 floats
  int* ri = (int*)(sm + 8);    // 8 ints
  float* bc = sm + 16;         // bc[0]=max, ((int*)bc)[1]=amax, bc[2]=lse
  for (int j = blockIdx.x; j < K; j += NWG) {
    size_t ro = (size_t)(t0 + j) * VD;
    float m = -3.4e38f; int ai = 0;
    for (int i = threadIdx.x; i < VD; i += NTHR) {
      float x = C.out_align[ro + i];
      if (x > m) { m = x; ai = i; }
    }
    #pragma unroll
    for (int msk = 32; msk; msk >>= 1) {
      float om = __shfl_xor(m, msk, 64);
      int oi = __shfl_xor(ai, msk, 64);
      if (om > m || (om == m && oi < ai)) { m = om; ai = oi; }
    }
    if (lane == 0) { rm[wid] = m; ri[wid] = ai; }
    __syncthreads();
    if (threadIdx.x == 0) {
      for (int w = 1; w < 8; ++w) {
        float om = rm[w]; int oi = ri[w];
        if (om > m || (om == m && oi < ai)) { m = om; ai = oi; }
      }
      bc[0] = m; ((int*)bc)[1] = ai;
      if (store_amax) C.amax[j] = ai;
    }
    __syncthreads();
    m = bc[0];
    float s = 0.f;
    for (int i = threadIdx.x; i < VD; i += NTHR) s += expf(C.out_align[ro + i] - m);
    #pragma unroll
    for (int msk = 32; msk; msk >>= 1) s += __shfl_xor(s, msk, 64);
    if (lane == 0) rm[wid] = s;
    __syncthreads();
    if (threadIdx.x == 0) {
      float tsum = 0.f;
      for (int w = 0; w < 8; ++w) tsum += rm[w];
      bc[2] = m + logf(tsum);
    }
    __syncthreads();
    float lse = bc[2];
    for (int i = threadIdx.x; i < VD; i += NTHR) C.out_align[ro + i] -= lse;
    __syncthreads();
  }
}

__global__ __launch_bounds__(NTHR) void decode_kernel(
    const float* enc, const float* emb, const float* Wih, const float* Whh,
    const float* bl, const float* Wpred, const float* bp, const float* Wjoin,
    const float* bj, const int* phon, float* out, float* wsf) {
  extern __shared__ float sm[];
  Ctx C;
  C.enc = enc; C.emb = emb; C.Wih = Wih; C.Whh = Whh; C.bl = bl;
  C.Wpred = Wpred; C.bp = bp; C.Wjoin = Wjoin; C.bj = bj; C.phon = phon;
  C.bar = (unsigned*)wsf;
  C.h = wsf + WSF_H; C.c = wsf + WSF_C; C.gates = wsf + WSF_G;
  C.preds = wsf + WSF_PRED; C.h2s = wsf + WSF_H2; C.c2s = wsf + WSF_C2;
  C.amax = (int*)(wsf + WSF_AMAX);
  C.out_align = out;
  C.out_pred  = out + (size_t)TT * VD;
  C.out_valid = out + (size_t)TT * VD + TT;

  const int gtid = blockIdx.x * NTHR + threadIdx.x;

  // warm-up predict from zero state with blank token
  chain_phase(C, sm, true, BLANK, 1, 0);
  grid_barrier(C.bar);
  if (gtid < 1024) C.h[gtid] = C.h2s[gtid];
  else if (gtid < 2048) C.c[gtid - 1024] = C.c2s[gtid - 1024];
  grid_barrier(C.bar);

  int t = 0, tp = 0, tok = BLANK;
  while (t < TT) {
    if (tp >= NPH) {
      // forced-blank tail: pred constant
      chain_phase(C, sm, false, tok, 1, tp);
      grid_barrier(C.bar);
      int Kt = TT - t;
      joiner_gemm(C, sm, t, Kt, false);
      grid_barrier(C.bar);
      reduce_phase(C, sm, t, Kt, false);
      for (int idx = gtid; idx < Kt; idx += NWG * NTHR) {
        C.out_pred[t + idx] = (float)BLANK;
        C.out_valid[t + idx] = 0.f;
      }
      break;
    }
    int K = SPEC;
    if (TT - t < K) K = TT - t;
    if (NPH - tp < K) K = NPH - tp;

    chain_phase(C, sm, false, tok, K, tp);
    grid_barrier(C.bar);
    joiner_gemm(C, sm, t, K, true);
    grid_barrier(C.bar);
    reduce_phase(C, sm, t, K, true);
    grid_barrier(C.bar);

    // decision: first blank index (parallel, redundant per WG -> uniform)
    int cand = K;
    if ((int)threadIdx.x < K) {
      if (C.amax[threadIdx.x] == BLANK) cand = threadIdx.x;
    }
    #pragma unroll
    for (int msk = 32; msk; msk >>= 1) {
      int o = __shfl_xor(cand, msk, 64);
      cand = min(cand, o);
    }
    {
      int* ric = (int*)sm;
      int wid = threadIdx.x >> 6, lane = threadIdx.x & 63;
      if (lane == 0) ric[wid] = cand;
      __syncthreads();
      if (threadIdx.x == 0) {
        int mn = ric[0];
        for (int w = 1; w < 8; ++w) mn = min(mn, ric[w]);
        ric[8] = mn;
      }
      __syncthreads();
      cand = ric[8];
      __syncthreads();
    }
    int jb = cand;
    int nacc = (jb < K) ? (jb + 1) : K;   // accepted steps
    int nadv = (jb < K) ? jb : K;         // non-blank count (tp advance)

    if (gtid < nacc) {
      C.out_pred[t + gtid] = (gtid == jb) ? (float)BLANK : (float)C.phon[tp + gtid];
      C.out_valid[t + gtid] = 1.f;
    }
    int src = nadv - 1;
    if (src >= 0) {
      if (gtid < 1024) C.h[gtid] = C.h2s[(size_t)src * 1024 + gtid];
      else if (gtid < 2048) C.c[gtid - 1024] = C.c2s[(size_t)src * 1024 + gtid - 1024];
    }
    if (nadv > 0) tok = C.phon[tp + nadv - 1];
    tp += nadv;
    t += nacc;
    grid_barrier(C.bar);
  }
}

extern "C" void kernel_launch(void* const* d_in, const int* in_sizes, int n_in,
                              void* d_out, int out_size, void* d_ws, size_t ws_size,
                              hipStream_t stream) {
  const float* enc   = (const float*)d_in[0];
  const float* emb   = (const float*)d_in[1];
  const float* Wih   = (const float*)d_in[2];
  const float* Whh   = (const float*)d_in[3];
  const float* bl    = (const float*)d_in[4];
  const float* Wpred = (const float*)d_in[5];
  const float* bp    = (const float*)d_in[6];
  const float* Wjoin = (const float*)d_in[7];
  const float* bj    = (const float*)d_in[8];
  const int*   phon  = (const int*)d_in[9];
  float* out = (float*)d_out;
  float* wsf = (float*)d_ws;

  // barrier counters must start at 0 every call (ws is poisoned once)
  hipMemsetAsync(d_ws, 0, WS_BAR_BYTES, stream);
  hipFuncSetAttribute((const void*)decode_kernel,
                      hipFuncAttributeMaxDynamicSharedMemorySize, SMEM_BYTES);

  void* args[] = { &enc, &emb, &Wih, &Whh, &bl, &Wpred, &bp, &Wjoin, &bj, &phon, &out, &wsf };
  hipError_t e = hipLaunchCooperativeKernel((void*)decode_kernel, dim3(NWG), dim3(NTHR),
                                            args, SMEM_BYTES, stream);
  if (e != hipSuccess) {
    // fallback: plain launch (256 WGs @ 1/CU are co-resident on 256-CU MI355X)
    decode_kernel<<<dim3(NWG), dim3(NTHR), SMEM_BYTES, stream>>>(
        enc, emb, Wih, Whh, bl, Wpred, bp, Wjoin, bj, phon, out, wsf);
  }
}

// Round 2
// 5867.952 us; speedup vs baseline: 4.0530x; 4.0530x over previous
//
#include <hip/hip_runtime.h>
#include <math.h>

#define TT     4000
#define DENC   1024
#define HD     1024
#define DEMB   512
#define VD     8193
#define NPH    800
#define BLANK  8192
#define NWG    256
#define NTHR   512
#define CHUNK  256
#define NSTEP  (NPH + 2)   // 802 sequential LSTM steps
#define NVT    65          // 65 v-tiles of 128 cover 8193

// ---- workspace (d_ws) layout ----
// bytes [0,4096): sync flags: arrive[256] u32 | release u32 @1024B | heavy bar[2] @1028B
#define FLAGS_BYTES 4096
// float offsets:
#define WSF_GB     1024                          // 2 x 4096 gate double buffer (sc1 data)
#define WSF_PREDS  (WSF_GB + 2 * 4096)           // (NPH+1) x 1024
#define WSF_PMAX   (WSF_PREDS + (NPH + 1) * 1024)
#define WSF_PSUM   (WSF_PMAX + TT * NVT)
#define WSF_PARG   (WSF_PSUM + TT * NVT)         // int
#define WSF_LSE    (WSF_PARG + TT * NVT)
#define WSF_END    (WSF_LSE + TT)                // ~1.61M floats = 6.2 MB

// ---- LDS layout (floats) ----
#define S_W    0        // 16 rows x (512 Wih | 1024 Whh)
#define S_WP   24576    // 4 x 1024 Wpred rows
#define S_X0   28672    // x double buffer
#define S_X1   29184
#define S_H    29696    // h (redundant per WG)
#define S_C    30720    // c (redundant per WG)
#define S_TOK  31744    // NSTEP ints (token chain)
#define S_RED  32546    // small reduction scratch
#define S_AMAX 32610    // CHUNK ints
#define SMEM_FLOATS 32866
#define SMEM_BYTES (SMEM_FLOATS * 4)
// GEMM phase reuses floats [0,3200): Wt[16][132] @0, Xt[16][68] @2112

struct Ctx {
  const float *enc, *emb, *Wih, *Whh, *bl, *Wpred, *bp, *Wjoin, *bj;
  const int* phon;
  float *gb, *preds, *pmax, *psum, *lse;
  int* parg;
  unsigned* flags;
  float *out_align, *out_pred, *out_valid;
};

__device__ __forceinline__ float dot4(float4 a, float4 b, float acc) {
  acc = fmaf(a.x, b.x, acc); acc = fmaf(a.y, b.y, acc);
  acc = fmaf(a.z, b.z, acc); acc = fmaf(a.w, b.w, acc);
  return acc;
}

__device__ __forceinline__ float sigmf(float x) { return 1.f / (1.f + expf(-x)); }

// merge two (max, sumexp, argmax) triplets; -1e30f sentinel keeps exp finite
__device__ __forceinline__ void combine3(float& m, float& s, int& am,
                                         float om, float os, int oa) {
  float mm = fmaxf(m, om);
  s = s * __expf(m - mm) + os * __expf(om - mm);
  if (om > m) am = oa;
  m = mm;
}

// ---- light barrier: flag-array + release word, NO cache flush/invalidate.
// Cross-WG data around it must travel via relaxed AGENT-scope atomics (sc1).
__device__ __forceinline__ void light_barrier(unsigned* flags, unsigned& ep) {
  unsigned* arrive  = flags;        // [256]
  unsigned* release = flags + 256;
  __builtin_amdgcn_s_waitcnt(0);    // drain this wave's vmem (stores ack'd at LLC)
  __syncthreads();                  // all waves drained + joined
  if (blockIdx.x == 0) {
    int tid = threadIdx.x;
    if (tid > 0 && tid < NWG) {
      while (__hip_atomic_load(&arrive[tid], __ATOMIC_RELAXED, __HIP_MEMORY_SCOPE_AGENT) != ep) {}
    }
    __syncthreads();
    if (tid == 0)
      __hip_atomic_store(release, ep, __ATOMIC_RELAXED, __HIP_MEMORY_SCOPE_AGENT);
  } else {
    if (threadIdx.x == 0) {
      __hip_atomic_store(&arrive[blockIdx.x], ep, __ATOMIC_RELAXED, __HIP_MEMORY_SCOPE_AGENT);
      while (__hip_atomic_load(release, __ATOMIC_RELAXED, __HIP_MEMORY_SCOPE_AGENT) != ep) {}
    }
    __syncthreads();
  }
  asm volatile("" ::: "memory");
  ep++;
}

// ---- heavy barrier: full fence (wbl2+inv via __threadfence) — for plain-store handoffs
__device__ __forceinline__ void heavy_barrier(unsigned* flags) {
  unsigned* bar = flags + 257;
  __syncthreads();
  if (threadIdx.x == 0) {
    __threadfence();
    unsigned g = __hip_atomic_load(&bar[1], __ATOMIC_RELAXED, __HIP_MEMORY_SCOPE_AGENT);
    unsigned v = __hip_atomic_fetch_add(&bar[0], 1u, __ATOMIC_RELAXED, __HIP_MEMORY_SCOPE_AGENT);
    if (v == (unsigned)(NWG - 1)) {
      __hip_atomic_store(&bar[0], 0u, __ATOMIC_RELAXED, __HIP_MEMORY_SCOPE_AGENT);
      __hip_atomic_store(&bar[1], g + 1u, __ATOMIC_RELEASE, __HIP_MEMORY_SCOPE_AGENT);
    } else {
      while (__hip_atomic_load(&bar[1], __ATOMIC_RELAXED, __HIP_MEMORY_SCOPE_AGENT) == g)
        __builtin_amdgcn_s_sleep(1);
    }
    __threadfence();
  }
  __syncthreads();
}

__device__ __forceinline__ float ld_coh(const float* p) {
  return __hip_atomic_load((const float*)p, __ATOMIC_RELAXED, __HIP_MEMORY_SCOPE_AGENT);
}

// ---- Phase 1: 802 sequential LSTM steps -> preds[0..800] (state indexed by tp only)
__device__ void chain_all(const Ctx& C, float* sm, unsigned& ep) {
  const int tid = threadIdx.x;
  const int wid = tid >> 6, lane = tid & 63;
  const int g0 = blockIdx.x * 16, p0 = blockIdx.x * 4;
  int* tok_sm = (int*)(sm + S_TOK);

  // stage per-WG weight slices into LDS
  for (int rr = 0; rr < 2; ++rr) {
    int r = wid * 2 + rr;
    const float4* a4 = (const float4*)(C.Wih + (size_t)(g0 + r) * DEMB);
    float4* dx = (float4*)(sm + S_W + r * 1536);
    #pragma unroll
    for (int i = 0; i < 2; ++i) dx[lane + 64 * i] = a4[lane + 64 * i];
    const float4* h4 = (const float4*)(C.Whh + (size_t)(g0 + r) * HD);
    float4* dh = (float4*)(sm + S_W + r * 1536 + 512);
    #pragma unroll
    for (int i = 0; i < 4; ++i) dh[lane + 64 * i] = h4[lane + 64 * i];
  }
  if (wid < 4) {
    const float4* p4 = (const float4*)(C.Wpred + (size_t)(p0 + wid) * HD);
    float4* dp = (float4*)(sm + S_WP + wid * 1024);
    #pragma unroll
    for (int i = 0; i < 4; ++i) dp[lane + 64 * i] = p4[lane + 64 * i];
  }
  for (int s = tid; s < NSTEP; s += NTHR)
    tok_sm[s] = (s < 2) ? BLANK : C.phon[s - 2];
  for (int i = tid; i < 1024; i += NTHR) { sm[S_H + i] = 0.f; sm[S_C + i] = 0.f; }
  sm[S_X0 + tid] = C.emb[(size_t)BLANK * DEMB + tid];
  float bias0 = C.bl[g0 + wid * 2];
  float bias1 = C.bl[g0 + wid * 2 + 1];
  float biasp = (wid < 4) ? C.bp[p0 + wid] : 0.f;
  __syncthreads();

  for (int s = 0; s < NSTEP; ++s) {
    const float* xb = sm + ((s & 1) ? S_X1 : S_X0);
    float4 xs0 = ((const float4*)xb)[lane * 2];
    float4 xs1 = ((const float4*)xb)[lane * 2 + 1];
    const float4* hp = (const float4*)(sm + S_H);
    float4 hs0 = hp[lane * 4], hs1 = hp[lane * 4 + 1];
    float4 hs2 = hp[lane * 4 + 2], hs3 = hp[lane * 4 + 3];
    float g01[2];
    #pragma unroll
    for (int rr = 0; rr < 2; ++rr) {
      const float* w = sm + S_W + (wid * 2 + rr) * 1536;
      const float4* wx = (const float4*)w;
      const float4* wh = (const float4*)(w + 512);
      float acc = 0.f;
      acc = dot4(wx[lane * 2], xs0, acc);
      acc = dot4(wx[lane * 2 + 1], xs1, acc);
      acc = dot4(wh[lane * 4], hs0, acc);
      acc = dot4(wh[lane * 4 + 1], hs1, acc);
      acc = dot4(wh[lane * 4 + 2], hs2, acc);
      acc = dot4(wh[lane * 4 + 3], hs3, acc);
      #pragma unroll
      for (int m = 32; m; m >>= 1) acc += __shfl_xor(acc, m, 64);
      g01[rr] = acc;
    }
    float* gbuf = C.gb + (s & 1) * 4096;
    if (lane == 0) {
      __hip_atomic_store(&gbuf[g0 + wid * 2], g01[0] + bias0,
                         __ATOMIC_RELAXED, __HIP_MEMORY_SCOPE_AGENT);
      __hip_atomic_store(&gbuf[g0 + wid * 2 + 1], g01[1] + bias1,
                         __ATOMIC_RELAXED, __HIP_MEMORY_SCOPE_AGENT);
    }
    // prefetch next token's embedding row into the other x buffer
    if (s + 1 < NSTEP) {
      int tn = tok_sm[s + 1];
      sm[((s & 1) ? S_X0 : S_X1) + tid] = C.emb[(size_t)tn * DEMB + tid];
    }
    light_barrier(C.flags, ep);
    // pointwise, redundant per WG (2 cells/thread); reads gates via sc1 loads
    {
      int c0 = tid, c1 = tid + 512;
      float gi0 = ld_coh(gbuf + c0),        gi1 = ld_coh(gbuf + c1);
      float gf0 = ld_coh(gbuf + 1024 + c0), gf1 = ld_coh(gbuf + 1024 + c1);
      float gg0 = ld_coh(gbuf + 2048 + c0), gg1 = ld_coh(gbuf + 2048 + c1);
      float go0 = ld_coh(gbuf + 3072 + c0), go1 = ld_coh(gbuf + 3072 + c1);
      float c2a = sigmf(gf0) * sm[S_C + c0] + sigmf(gi0) * tanhf(gg0);
      float h2a = sigmf(go0) * tanhf(c2a);
      float c2b = sigmf(gf1) * sm[S_C + c1] + sigmf(gi1) * tanhf(gg1);
      float h2b = sigmf(go1) * tanhf(c2b);
      sm[S_C + c0] = c2a; sm[S_H + c0] = h2a;
      sm[S_C + c1] = c2b; sm[S_H + c1] = h2b;
    }
    __syncthreads();
    if (s >= 1 && wid < 4) {  // pred(s-1) = Wpred @ h + bp
      const float4* wp4 = (const float4*)(sm + S_WP + wid * 1024);
      const float4* hh = (const float4*)(sm + S_H);
      float acc = 0.f;
      acc = dot4(wp4[lane * 4], hh[lane * 4], acc);
      acc = dot4(wp4[lane * 4 + 1], hh[lane * 4 + 1], acc);
      acc = dot4(wp4[lane * 4 + 2], hh[lane * 4 + 2], acc);
      acc = dot4(wp4[lane * 4 + 3], hh[lane * 4 + 3], acc);
      #pragma unroll
      for (int m = 32; m; m >>= 1) acc += __shfl_xor(acc, m, 64);
      if (lane == 0)
        C.preds[(size_t)(s - 1) * 1024 + p0 + wid] = acc + biasp;
    }
  }
}

// ---- Phase 2: joiner GEMM 128v x 64j tiles + fused per-tile softmax partials
// pi0 >= 0: row j uses preds[pi0+j] (speculative); pi0 < 0: all rows use preds[NPH]
__device__ void joiner_gemm(const Ctx& C, float* sm, int t0, int K, int pi0) {
  float* Wt = sm;          // [16][132]
  float* Xt = sm + 2112;   // [16][68]
  const int tid = threadIdx.x;
  const int tx = tid & 31, ty = tid >> 5;
  int jt_n = (K + 63) >> 6;
  int ntiles = jt_n * NVT;
  for (int tile = blockIdx.x; tile < ntiles; tile += NWG) {
    int vt = tile % NVT, jt = tile / NVT;
    int v0 = vt * 128, j0 = jt * 64;
    float acc[4][4];
    #pragma unroll
    for (int a = 0; a < 4; ++a)
      #pragma unroll
      for (int b = 0; b < 4; ++b) acc[a][b] = 0.f;

    for (int kk = 0; kk < 1024; kk += 16) {
      {
        int r = tid >> 2, seg = tid & 3;
        int v = v0 + r;
        float4 w = make_float4(0.f, 0.f, 0.f, 0.f);
        if (v < VD) w = ((const float4*)(C.Wjoin + (size_t)v * 1024 + kk))[seg];
        Wt[(seg * 4 + 0) * 132 + r] = w.x;
        Wt[(seg * 4 + 1) * 132 + r] = w.y;
        Wt[(seg * 4 + 2) * 132 + r] = w.z;
        Wt[(seg * 4 + 3) * 132 + r] = w.w;
      }
      if (tid < 256) {
        int r = tid >> 2, seg = tid & 3;
        int j = j0 + r;
        float4 xv = make_float4(0.f, 0.f, 0.f, 0.f);
        if (j < K) {
          int pi = (pi0 < 0) ? NPH : (pi0 + j);
          float4 e = ((const float4*)(C.enc + (size_t)(t0 + j) * DENC + kk))[seg];
          float4 p = ((const float4*)(C.preds + (size_t)pi * 1024 + kk))[seg];
          xv.x = fmaxf(e.x + p.x, 0.f);
          xv.y = fmaxf(e.y + p.y, 0.f);
          xv.z = fmaxf(e.z + p.z, 0.f);
          xv.w = fmaxf(e.w + p.w, 0.f);
        }
        Xt[(seg * 4 + 0) * 68 + r] = xv.x;
        Xt[(seg * 4 + 1) * 68 + r] = xv.y;
        Xt[(seg * 4 + 2) * 68 + r] = xv.z;
        Xt[(seg * 4 + 3) * 68 + r] = xv.w;
      }
      __syncthreads();
      #pragma unroll
      for (int k = 0; k < 16; ++k) {
        float4 a = *(const float4*)(Wt + k * 132 + (tx << 2));
        float4 b = *(const float4*)(Xt + k * 68 + (ty << 2));
        acc[0][0] = fmaf(a.x, b.x, acc[0][0]);
        acc[1][0] = fmaf(a.y, b.x, acc[1][0]);
        acc[2][0] = fmaf(a.z, b.x, acc[2][0]);
        acc[3][0] = fmaf(a.w, b.x, acc[3][0]);
        acc[0][1] = fmaf(a.x, b.y, acc[0][1]);
        acc[1][1] = fmaf(a.y, b.y, acc[1][1]);
        acc[2][1] = fmaf(a.z, b.y, acc[2][1]);
        acc[3][1] = fmaf(a.w, b.y, acc[3][1]);
        acc[0][2] = fmaf(a.x, b.z, acc[0][2]);
        acc[1][2] = fmaf(a.y, b.z, acc[1][2]);
        acc[2][2] = fmaf(a.z, b.z, acc[2][2]);
        acc[3][2] = fmaf(a.w, b.z, acc[3][2]);
        acc[0][3] = fmaf(a.x, b.w, acc[0][3]);
        acc[1][3] = fmaf(a.y, b.w, acc[1][3]);
        acc[2][3] = fmaf(a.z, b.w, acc[2][3]);
        acc[3][3] = fmaf(a.w, b.w, acc[3][3]);
      }
      __syncthreads();
    }
    // epilogue: logits write + per-tile (max, argmax, sumexp) partials
    int vb = v0 + (tx << 2);
    int jb0 = j0 + (ty << 2);
    float bjv[4];
    #pragma unroll
    for (int q = 0; q < 4; ++q) bjv[q] = (vb + q < VD) ? C.bj[vb + q] : 0.f;
    #pragma unroll
    for (int jj = 0; jj < 4; ++jj) {
      int j = jb0 + jj;
      if (j >= K) continue;
      size_t ro = (size_t)(t0 + j) * VD;
      float lg[4];
      float m = -1e30f; int am = vb;
      #pragma unroll
      for (int q = 0; q < 4; ++q) {
        int v = vb + q;
        if (v < VD) {
          lg[q] = acc[q][jj] + bjv[q];
          C.out_align[ro + v] = lg[q];
          if (lg[q] > m) { m = lg[q]; am = v; }
        } else lg[q] = -1e30f;
      }
      float ss = 0.f;
      #pragma unroll
      for (int q = 0; q < 4; ++q)
        if (vb + q < VD) ss += __expf(lg[q] - m);
      #pragma unroll
      for (int msk = 16; msk; msk >>= 1) {
        float om = __shfl_xor(m, msk, 64);
        float os = __shfl_xor(ss, msk, 64);
        int oa = __shfl_xor(am, msk, 64);
        combine3(m, ss, am, om, os, oa);
      }
      if (tx == 0) {
        size_t pb = (size_t)(t0 + j) * NVT + vt;
        __hip_atomic_store(&C.pmax[pb], m, __ATOMIC_RELAXED, __HIP_MEMORY_SCOPE_AGENT);
        __hip_atomic_store(&C.psum[pb], ss, __ATOMIC_RELAXED, __HIP_MEMORY_SCOPE_AGENT);
        __hip_atomic_store(&C.parg[pb], am, __ATOMIC_RELAXED, __HIP_MEMORY_SCOPE_AGENT);
      }
    }
  }
}

// merge 65 tile-partials of one row (all 64 lanes participate; result in all lanes)
__device__ __forceinline__ void merge_row(const Ctx& C, int row, int lane,
                                          float& m, float& s, int& am) {
  size_t b = (size_t)row * NVT;
  m = ld_coh(C.pmax + b + lane);
  s = ld_coh(C.psum + b + lane);
  am = __hip_atomic_load(&C.parg[b + lane], __ATOMIC_RELAXED, __HIP_MEMORY_SCOPE_AGENT);
  if (lane == 0) {
    float om = ld_coh(C.pmax + b + 64);
    float os = ld_coh(C.psum + b + 64);
    int oa = __hip_atomic_load(&C.parg[b + 64], __ATOMIC_RELAXED, __HIP_MEMORY_SCOPE_AGENT);
    combine3(m, s, am, om, os, oa);
  }
  #pragma unroll
  for (int msk = 32; msk; msk >>= 1) {
    float om = __shfl_xor(m, msk, 64);
    float os = __shfl_xor(s, msk, 64);
    int oa = __shfl_xor(am, msk, 64);
    combine3(m, s, am, om, os, oa);
  }
}

__global__ __launch_bounds__(NTHR) void decode_kernel(
    const float* enc, const float* emb, const float* Wih, const float* Whh,
    const float* bl, const float* Wpred, const float* bp, const float* Wjoin,
    const float* bj, const int* phon, float* out, float* wsf) {
  extern __shared__ float sm[];
  Ctx C;
  C.enc = enc; C.emb = emb; C.Wih = Wih; C.Whh = Whh; C.bl = bl;
  C.Wpred = Wpred; C.bp = bp; C.Wjoin = Wjoin; C.bj = bj; C.phon = phon;
  C.flags = (unsigned*)wsf;
  C.gb = wsf + WSF_GB;
  C.preds = wsf + WSF_PREDS;
  C.pmax = wsf + WSF_PMAX;
  C.psum = wsf + WSF_PSUM;
  C.parg = (int*)(wsf + WSF_PARG);
  C.lse = wsf + WSF_LSE;
  C.out_align = out;
  C.out_pred  = out + (size_t)TT * VD;
  C.out_valid = out + (size_t)TT * VD + TT;

  const int tid = threadIdx.x;
  const int wid = tid >> 6, lane = tid & 63;
  unsigned ep = 1;

  // Phase 1: full predictor chain (sequential part), preds[0..800]
  chain_all(C, sm, ep);
  heavy_barrier(C.flags);   // flush preds (plain stores) for all readers

  // Phase 2: speculative chunked decode
  int t = 0, tp = 0;
  while (t < TT && tp < NPH) {
    int K = CHUNK;
    if (TT - t < K) K = TT - t;
    if (NPH - tp < K) K = NPH - tp;
    joiner_gemm(C, sm, t, K, tp);
    light_barrier(C.flags, ep);

    // merge partials + first-blank decision (redundant per WG -> uniform)
    int* amax_l = (int*)(sm + S_AMAX);
    for (int j = wid; j < K; j += 8) {
      float m, s; int am;
      merge_row(C, t + j, lane, m, s, am);
      if (lane == 0) {
        amax_l[j] = am;
        C.lse[t + j] = m + logf(s);
      }
    }
    __syncthreads();
    int cand = K;
    if (tid < K && amax_l[tid] == BLANK) cand = tid;
    #pragma unroll
    for (int msk = 32; msk; msk >>= 1) cand = min(cand, __shfl_xor(cand, msk, 64));
    int* red = (int*)(sm + S_RED);
    if (lane == 0) red[wid] = cand;
    __syncthreads();
    if (tid == 0) {
      int mn = red[0];
      for (int w = 1; w < 8; ++w) mn = min(mn, red[w]);
      red[8] = mn;
    }
    __syncthreads();
    int jb = red[8];
    __syncthreads();
    int nacc = (jb < K) ? jb + 1 : K;
    int nadv = (jb < K) ? jb : K;
    if (blockIdx.x == 0) {
      int* tok_sm = (int*)(sm + S_TOK);
      for (int j = tid; j < nacc; j += NTHR) {
        C.out_pred[t + j] = (j == jb) ? (float)BLANK : (float)tok_sm[tp + j + 2];
        C.out_valid[t + j] = 1.f;
      }
    }
    t += nacc; tp += nadv;
    // blank rollback: rows > jb get rewritten next chunk -> must flush dirty
    // logits/lse copies before the rewrite (avoids two-XCD dirty-line races)
    if (jb < K) heavy_barrier(C.flags);
  }

  // Phase 3: forced-blank tail (pred constant = preds[NPH])
  if (t < TT) {
    int Kt = TT - t;
    joiner_gemm(C, sm, t, Kt, -1);
    light_barrier(C.flags, ep);
    for (int i = blockIdx.x * 8 + wid; i < Kt; i += NWG * 8) {
      float m, s; int am;
      merge_row(C, t + i, lane, m, s, am);
      if (lane == 0) C.lse[t + i] = m + logf(s);
    }
    const int gtid = blockIdx.x * NTHR + tid;
    for (int i = gtid; i < Kt; i += NWG * NTHR) {
      C.out_pred[t + i] = (float)BLANK;
      C.out_valid[t + i] = 0.f;
    }
  }

  heavy_barrier(C.flags);   // flush all logits + lse before final pass

  // Phase 4: logp = logits - lse (single streaming pass)
  for (int row = blockIdx.x; row < TT; row += NWG) {
    float l = C.lse[row];
    float* p = C.out_align + (size_t)row * VD;
    for (int i = tid; i < VD; i += NTHR) p[i] -= l;
  }
}

extern "C" void kernel_launch(void* const* d_in, const int* in_sizes, int n_in,
                              void* d_out, int out_size, void* d_ws, size_t ws_size,
                              hipStream_t stream) {
  const float* enc   = (const float*)d_in[0];
  const float* emb   = (const float*)d_in[1];
  const float* Wih   = (const float*)d_in[2];
  const float* Whh   = (const float*)d_in[3];
  const float* bl    = (const float*)d_in[4];
  const float* Wpred = (const float*)d_in[5];
  const float* bp    = (const float*)d_in[6];
  const float* Wjoin = (const float*)d_in[7];
  const float* bj    = (const float*)d_in[8];
  const int*   phon  = (const int*)d_in[9];
  float* out = (float*)d_out;
  float* wsf = (float*)d_ws;

  // sync flags must start at 0 every call (ws is poisoned once, not re-poisoned)
  hipMemsetAsync(d_ws, 0, FLAGS_BYTES, stream);
  hipFuncSetAttribute((const void*)decode_kernel,
                      hipFuncAttributeMaxDynamicSharedMemorySize, SMEM_BYTES);

  void* args[] = { &enc, &emb, &Wih, &Whh, &bl, &Wpred, &bp, &Wjoin, &bj, &phon, &out, &wsf };
  hipError_t e = hipLaunchCooperativeKernel((void*)decode_kernel, dim3(NWG), dim3(NTHR),
                                            args, SMEM_BYTES, stream);
  if (e != hipSuccess) {
    // fallback: plain launch (256 WGs @ 1/CU are co-resident on 256-CU MI355X)
    decode_kernel<<<dim3(NWG), dim3(NTHR), SMEM_BYTES, stream>>>(
        enc, emb, Wih, Whh, bl, Wpred, bp, Wjoin, bj, phon, out, wsf);
  }
}

// Round 3
// 4452.007 us; speedup vs baseline: 5.3421x; 1.3180x over previous
//
#include <hip/hip_runtime.h>
#include <math.h>

#define TT     4000
#define DENC   1024
#define HD     1024
#define DEMB   512
#define VD     8193
#define NPH    800
#define BLANK  8192
#define NWG    256
#define NTHR   512
#define CHUNK  256
#define NSTEP  (NPH + 2)   // 802 sequential LSTM steps
#define NVT    65          // 65 v-tiles of 128 cover 8193

// ---- workspace (d_ws) layout ----
// [0,4096): light/heavy barrier flags. [4096, 20480): tagged h-exchange (2x1024 u64).
#define FLAGS_BYTES  4096
#define MEMSET_BYTES 20480
// float offsets from wsf:
#define WSF_HX     1024                          // u64[2][1024] tagged h exchange
#define WSF_HHIST  5120                          // NSTEP x 1024 (h after each step)
#define WSF_PREDS  (WSF_HHIST + NSTEP * 1024)    // (NPH+1) x 1024
#define WSF_PMAX   (WSF_PREDS + (NPH + 1) * 1024)
#define WSF_PSUM   (WSF_PMAX + TT * NVT)
#define WSF_PARG   (WSF_PSUM + TT * NVT)         // int
#define WSF_LSE    (WSF_PARG + TT * NVT)
#define WSF_END    (WSF_LSE + TT)                // ~9.7 MB

// ---- LDS layout (floats) ----
// chain uses [0, 3092); GEMM phases reuse [0, 3200) (Wt[16][132] @0, Xt[16][68] @2112)
#define S_XH   0        // [2][1536]: x (0..511) | h (512..1535), double-buffered by step parity
#define S_GS   3072     // 16 gate row sums
#define S_C4   3088     // 4 local cell states
#define S_TOK  3264     // NSTEP ints (token chain)
#define S_RED  4066     // small reduction scratch (16)
#define S_AMAX 4082     // CHUNK ints
#define SMEM_FLOATS 4352
#define SMEM_BYTES (SMEM_FLOATS * 4)

struct Ctx {
  const float *enc, *emb, *Wih, *Whh, *bl, *Wpred, *bp, *Wjoin, *bj;
  const int* phon;
  unsigned long long* hx;
  float *hhist, *preds, *pmax, *psum, *lse;
  int* parg;
  unsigned* flags;
  float *out_align, *out_pred, *out_valid;
};

__device__ __forceinline__ float dot4(float4 a, float4 b, float acc) {
  acc = fmaf(a.x, b.x, acc); acc = fmaf(a.y, b.y, acc);
  acc = fmaf(a.z, b.z, acc); acc = fmaf(a.w, b.w, acc);
  return acc;
}

__device__ __forceinline__ float sigmf(float x) { return 1.f / (1.f + expf(-x)); }

__device__ __forceinline__ void combine3(float& m, float& s, int& am,
                                         float om, float os, int oa) {
  float mm = fmaxf(m, om);
  s = s * __expf(m - mm) + os * __expf(om - mm);
  if (om > m) am = oa;
  m = mm;
}

// ---- light barrier: flag-array + release word, no cache flush (data via sc1 atomics)
__device__ __forceinline__ void light_barrier(unsigned* flags, unsigned& ep) {
  unsigned* arrive  = flags;        // [256]
  unsigned* release = flags + 256;
  __builtin_amdgcn_s_waitcnt(0);
  __syncthreads();
  if (blockIdx.x == 0) {
    int tid = threadIdx.x;
    if (tid > 0 && tid < NWG) {
      while (__hip_atomic_load(&arrive[tid], __ATOMIC_RELAXED, __HIP_MEMORY_SCOPE_AGENT) != ep) {}
    }
    __syncthreads();
    if (tid == 0)
      __hip_atomic_store(release, ep, __ATOMIC_RELAXED, __HIP_MEMORY_SCOPE_AGENT);
  } else {
    if (threadIdx.x == 0) {
      __hip_atomic_store(&arrive[blockIdx.x], ep, __ATOMIC_RELAXED, __HIP_MEMORY_SCOPE_AGENT);
      while (__hip_atomic_load(release, __ATOMIC_RELAXED, __HIP_MEMORY_SCOPE_AGENT) != ep) {}
    }
    __syncthreads();
  }
  asm volatile("" ::: "memory");
  ep++;
}

// ---- heavy barrier: full fence (wbl2+inv) — for plain-store handoffs
__device__ __forceinline__ void heavy_barrier(unsigned* flags) {
  unsigned* bar = flags + 257;
  __syncthreads();
  if (threadIdx.x == 0) {
    __threadfence();
    unsigned g = __hip_atomic_load(&bar[1], __ATOMIC_RELAXED, __HIP_MEMORY_SCOPE_AGENT);
    unsigned v = __hip_atomic_fetch_add(&bar[0], 1u, __ATOMIC_RELAXED, __HIP_MEMORY_SCOPE_AGENT);
    if (v == (unsigned)(NWG - 1)) {
      __hip_atomic_store(&bar[0], 0u, __ATOMIC_RELAXED, __HIP_MEMORY_SCOPE_AGENT);
      __hip_atomic_store(&bar[1], g + 1u, __ATOMIC_RELEASE, __HIP_MEMORY_SCOPE_AGENT);
    } else {
      while (__hip_atomic_load(&bar[1], __ATOMIC_RELAXED, __HIP_MEMORY_SCOPE_AGENT) == g)
        __builtin_amdgcn_s_sleep(1);
    }
    __threadfence();
  }
  __syncthreads();
}

__device__ __forceinline__ float ld_coh(const float* p) {
  return __hip_atomic_load((const float*)p, __ATOMIC_RELAXED, __HIP_MEMORY_SCOPE_AGENT);
}

// ---- Phase 1: 802 sequential LSTM steps. WG b owns cells 4b..4b+3 (rows 1024q+4b+j):
// gate matvec from REGISTER-resident W rows (conflict-free LDS reads of x|h only),
// WG-local pointwise, h exchanged grid-wide as tag-packed u64 atomics (1 LLC trip).
__device__ void chain_all(const Ctx& C, float* sm) {
  const int tid = threadIdx.x;
  const int w = tid >> 6, l = tid & 63;
  const int b = blockIdx.x;
  int* tok_sm = (int*)(sm + S_TOK);

  for (int s = tid; s < NSTEP; s += NTHR)
    tok_sm[s] = (s < 2) ? BLANK : C.phon[s - 2];

  // register-load this thread's W slices: rows rr0=2w, rr1=2w+1 (rr=q*4+j)
  float4 W0[6], W1[6];
  {
    int rr0 = 2 * w, rr1 = 2 * w + 1;
    int gr0 = ((rr0 >> 2) << 10) + 4 * b + (rr0 & 3);
    int gr1 = ((rr1 >> 2) << 10) + 4 * b + (rr1 & 3);
    const float4* ih0 = (const float4*)(C.Wih + (size_t)gr0 * DEMB);
    const float4* hh0 = (const float4*)(C.Whh + (size_t)gr0 * HD);
    const float4* ih1 = (const float4*)(C.Wih + (size_t)gr1 * DEMB);
    const float4* hh1 = (const float4*)(C.Whh + (size_t)gr1 * HD);
    W0[0] = ih0[l];       W0[1] = ih0[64 + l];
    W0[2] = hh0[l];       W0[3] = hh0[64 + l];
    W0[4] = hh0[128 + l]; W0[5] = hh0[192 + l];
    W1[0] = ih1[l];       W1[1] = ih1[64 + l];
    W1[2] = hh1[l];       W1[3] = hh1[64 + l];
    W1[4] = hh1[128 + l]; W1[5] = hh1[192 + l];
  }
  float bi = 0.f, bf = 0.f, bg = 0.f, bo = 0.f;
  if (tid < 4) {
    bi = C.bl[4 * b + tid];
    bf = C.bl[1024 + 4 * b + tid];
    bg = C.bl[2048 + 4 * b + tid];
    bo = C.bl[3072 + 4 * b + tid];
    sm[S_C4 + tid] = 0.f;
  }
  for (int i = tid; i < 1536; i += NTHR) sm[S_XH + i] = 0.f;   // h(0)=0
  if (tid < 512) sm[S_XH + tid] = C.emb[(size_t)BLANK * DEMB + tid];  // x(0)
  __syncthreads();

  unsigned long long* hx = C.hx;
  for (int s = 0; s < NSTEP; ++s) {
    int p = s & 1;
    const float4* xh4 = (const float4*)(sm + S_XH + p * 1536);
    float a0 = 0.f, a1 = 0.f;
    #pragma unroll
    for (int i = 0; i < 6; ++i) {
      float4 v = xh4[i * 64 + l];
      a0 = dot4(W0[i], v, a0);
      a1 = dot4(W1[i], v, a1);
    }
    #pragma unroll
    for (int m = 32; m; m >>= 1) {
      a0 += __shfl_xor(a0, m, 64);
      a1 += __shfl_xor(a1, m, 64);
    }
    if (l == 0) { sm[S_GS + 2 * w] = a0; sm[S_GS + 2 * w + 1] = a1; }
    // prefetch x(s+1) into the other buffer
    if (s + 1 < NSTEP && tid < 512)
      sm[S_XH + (1 - p) * 1536 + tid] = C.emb[(size_t)tok_sm[s + 1] * DEMB + tid];
    __syncthreads();
    if (tid < 4) {
      int j = tid;
      float gi = sm[S_GS + j]      + bi;
      float gf = sm[S_GS + 4 + j]  + bf;
      float gg = sm[S_GS + 8 + j]  + bg;
      float go = sm[S_GS + 12 + j] + bo;
      float cc = sm[S_C4 + j];
      float c2 = sigmf(gf) * cc + sigmf(gi) * tanhf(gg);
      float h2 = sigmf(go) * tanhf(c2);
      sm[S_C4 + j] = c2;
      int cell = 4 * b + j;
      C.hhist[(size_t)s * HD + cell] = h2;                       // plain (heavy-barrier later)
      unsigned long long pk = ((unsigned long long)(unsigned)(s + 1) << 32)
                            | (unsigned long long)__float_as_uint(h2);
      __hip_atomic_store(&hx[(1 - p) * 1024 + cell], pk,
                         __ATOMIC_RELAXED, __HIP_MEMORY_SCOPE_AGENT);
    }
    if (s + 1 < NSTEP) {
      unsigned tg = (unsigned)(s + 1);
      #pragma unroll
      for (int kq = 0; kq < 2; ++kq) {
        int k = tid + kq * 512;
        unsigned long long v;
        do {
          v = __hip_atomic_load(&hx[(1 - p) * 1024 + k],
                                __ATOMIC_RELAXED, __HIP_MEMORY_SCOPE_AGENT);
        } while ((unsigned)(v >> 32) != tg);
        sm[S_XH + (1 - p) * 1536 + 512 + k] = __uint_as_float((unsigned)v);
      }
    }
    __syncthreads();
  }
}

// ---- Phase 1b: preds[i] = W_pred @ hhist[i+1] + bp, i in [0, NPH]  (batched GEMM)
__device__ void preds_gemm(const Ctx& C, float* sm) {
  float* Wt = sm;          // [16][132]
  float* Xt = sm + 2112;   // [16][68]
  const int tid = threadIdx.x;
  const int tx = tid & 31, ty = tid >> 5;
  const int NJT = (NPH + 1 + 63) >> 6;   // 13
  int ntiles = 8 * NJT;
  for (int tile = blockIdx.x; tile < ntiles; tile += NWG) {
    int vt = tile & 7, jt = tile >> 3;
    int v0 = vt * 128, j0 = jt * 64;
    float acc[4][4];
    #pragma unroll
    for (int a = 0; a < 4; ++a)
      #pragma unroll
      for (int q = 0; q < 4; ++q) acc[a][q] = 0.f;
    for (int kk = 0; kk < 1024; kk += 16) {
      {
        int r = tid >> 2, seg = tid & 3;
        float4 wv = ((const float4*)(C.Wpred + (size_t)(v0 + r) * HD + kk))[seg];
        Wt[(seg * 4 + 0) * 132 + r] = wv.x;
        Wt[(seg * 4 + 1) * 132 + r] = wv.y;
        Wt[(seg * 4 + 2) * 132 + r] = wv.z;
        Wt[(seg * 4 + 3) * 132 + r] = wv.w;
      }
      if (tid < 256) {
        int r = tid >> 2, seg = tid & 3;
        int j = j0 + r;
        float4 xv = make_float4(0.f, 0.f, 0.f, 0.f);
        if (j <= NPH) xv = ((const float4*)(C.hhist + (size_t)(j + 1) * HD + kk))[seg];
        Xt[(seg * 4 + 0) * 68 + r] = xv.x;
        Xt[(seg * 4 + 1) * 68 + r] = xv.y;
        Xt[(seg * 4 + 2) * 68 + r] = xv.z;
        Xt[(seg * 4 + 3) * 68 + r] = xv.w;
      }
      __syncthreads();
      #pragma unroll
      for (int k = 0; k < 16; ++k) {
        float4 a = *(const float4*)(Wt + k * 132 + (tx << 2));
        float4 bq = *(const float4*)(Xt + k * 68 + (ty << 2));
        acc[0][0] = fmaf(a.x, bq.x, acc[0][0]); acc[1][0] = fmaf(a.y, bq.x, acc[1][0]);
        acc[2][0] = fmaf(a.z, bq.x, acc[2][0]); acc[3][0] = fmaf(a.w, bq.x, acc[3][0]);
        acc[0][1] = fmaf(a.x, bq.y, acc[0][1]); acc[1][1] = fmaf(a.y, bq.y, acc[1][1]);
        acc[2][1] = fmaf(a.z, bq.y, acc[2][1]); acc[3][1] = fmaf(a.w, bq.y, acc[3][1]);
        acc[0][2] = fmaf(a.x, bq.z, acc[0][2]); acc[1][2] = fmaf(a.y, bq.z, acc[1][2]);
        acc[2][2] = fmaf(a.z, bq.z, acc[2][2]); acc[3][2] = fmaf(a.w, bq.z, acc[3][2]);
        acc[0][3] = fmaf(a.x, bq.w, acc[0][3]); acc[1][3] = fmaf(a.y, bq.w, acc[1][3]);
        acc[2][3] = fmaf(a.z, bq.w, acc[2][3]); acc[3][3] = fmaf(a.w, bq.w, acc[3][3]);
      }
      __syncthreads();
    }
    int vb = v0 + (tx << 2), jb0 = j0 + (ty << 2);
    #pragma unroll
    for (int jj = 0; jj < 4; ++jj) {
      int j = jb0 + jj;
      if (j > NPH) continue;
      #pragma unroll
      for (int q = 0; q < 4; ++q)
        C.preds[(size_t)j * 1024 + vb + q] = acc[q][jj] + C.bp[vb + q];
    }
  }
}

// ---- Phase 2/3: joiner GEMM 128v x 64j tiles + fused per-tile softmax partials
__device__ void joiner_gemm(const Ctx& C, float* sm, int t0, int K, int pi0) {
  float* Wt = sm;          // [16][132]
  float* Xt = sm + 2112;   // [16][68]
  const int tid = threadIdx.x;
  const int tx = tid & 31, ty = tid >> 5;
  int jt_n = (K + 63) >> 6;
  int ntiles = jt_n * NVT;
  for (int tile = blockIdx.x; tile < ntiles; tile += NWG) {
    int vt = tile % NVT, jt = tile / NVT;
    int v0 = vt * 128, j0 = jt * 64;
    float acc[4][4];
    #pragma unroll
    for (int a = 0; a < 4; ++a)
      #pragma unroll
      for (int q = 0; q < 4; ++q) acc[a][q] = 0.f;

    for (int kk = 0; kk < 1024; kk += 16) {
      {
        int r = tid >> 2, seg = tid & 3;
        int v = v0 + r;
        float4 wv = make_float4(0.f, 0.f, 0.f, 0.f);
        if (v < VD) wv = ((const float4*)(C.Wjoin + (size_t)v * 1024 + kk))[seg];
        Wt[(seg * 4 + 0) * 132 + r] = wv.x;
        Wt[(seg * 4 + 1) * 132 + r] = wv.y;
        Wt[(seg * 4 + 2) * 132 + r] = wv.z;
        Wt[(seg * 4 + 3) * 132 + r] = wv.w;
      }
      if (tid < 256) {
        int r = tid >> 2, seg = tid & 3;
        int j = j0 + r;
        float4 xv = make_float4(0.f, 0.f, 0.f, 0.f);
        if (j < K) {
          int pi = (pi0 < 0) ? NPH : (pi0 + j);
          float4 e = ((const float4*)(C.enc + (size_t)(t0 + j) * DENC + kk))[seg];
          float4 pr = ((const float4*)(C.preds + (size_t)pi * 1024 + kk))[seg];
          xv.x = fmaxf(e.x + pr.x, 0.f);
          xv.y = fmaxf(e.y + pr.y, 0.f);
          xv.z = fmaxf(e.z + pr.z, 0.f);
          xv.w = fmaxf(e.w + pr.w, 0.f);
        }
        Xt[(seg * 4 + 0) * 68 + r] = xv.x;
        Xt[(seg * 4 + 1) * 68 + r] = xv.y;
        Xt[(seg * 4 + 2) * 68 + r] = xv.z;
        Xt[(seg * 4 + 3) * 68 + r] = xv.w;
      }
      __syncthreads();
      #pragma unroll
      for (int k = 0; k < 16; ++k) {
        float4 a = *(const float4*)(Wt + k * 132 + (tx << 2));
        float4 bq = *(const float4*)(Xt + k * 68 + (ty << 2));
        acc[0][0] = fmaf(a.x, bq.x, acc[0][0]); acc[1][0] = fmaf(a.y, bq.x, acc[1][0]);
        acc[2][0] = fmaf(a.z, bq.x, acc[2][0]); acc[3][0] = fmaf(a.w, bq.x, acc[3][0]);
        acc[0][1] = fmaf(a.x, bq.y, acc[0][1]); acc[1][1] = fmaf(a.y, bq.y, acc[1][1]);
        acc[2][1] = fmaf(a.z, bq.y, acc[2][1]); acc[3][1] = fmaf(a.w, bq.y, acc[3][1]);
        acc[0][2] = fmaf(a.x, bq.z, acc[0][2]); acc[1][2] = fmaf(a.y, bq.z, acc[1][2]);
        acc[2][2] = fmaf(a.z, bq.z, acc[2][2]); acc[3][2] = fmaf(a.w, bq.z, acc[3][2]);
        acc[0][3] = fmaf(a.x, bq.w, acc[0][3]); acc[1][3] = fmaf(a.y, bq.w, acc[1][3]);
        acc[2][3] = fmaf(a.z, bq.w, acc[2][3]); acc[3][3] = fmaf(a.w, bq.w, acc[3][3]);
      }
      __syncthreads();
    }
    int vb = v0 + (tx << 2);
    int jb0 = j0 + (ty << 2);
    float bjv[4];
    #pragma unroll
    for (int q = 0; q < 4; ++q) bjv[q] = (vb + q < VD) ? C.bj[vb + q] : 0.f;
    #pragma unroll
    for (int jj = 0; jj < 4; ++jj) {
      int j = jb0 + jj;
      if (j >= K) continue;
      size_t ro = (size_t)(t0 + j) * VD;
      float lg[4];
      float m = -1e30f; int am = vb;
      #pragma unroll
      for (int q = 0; q < 4; ++q) {
        int v = vb + q;
        if (v < VD) {
          lg[q] = acc[q][jj] + bjv[q];
          C.out_align[ro + v] = lg[q];
          if (lg[q] > m) { m = lg[q]; am = v; }
        } else lg[q] = -1e30f;
      }
      float ss = 0.f;
      #pragma unroll
      for (int q = 0; q < 4; ++q)
        if (vb + q < VD) ss += __expf(lg[q] - m);
      #pragma unroll
      for (int msk = 16; msk; msk >>= 1) {
        float om = __shfl_xor(m, msk, 64);
        float os = __shfl_xor(ss, msk, 64);
        int oa = __shfl_xor(am, msk, 64);
        combine3(m, ss, am, om, os, oa);
      }
      if (tx == 0) {
        size_t pb = (size_t)(t0 + j) * NVT + vt;
        __hip_atomic_store(&C.pmax[pb], m, __ATOMIC_RELAXED, __HIP_MEMORY_SCOPE_AGENT);
        __hip_atomic_store(&C.psum[pb], ss, __ATOMIC_RELAXED, __HIP_MEMORY_SCOPE_AGENT);
        __hip_atomic_store(&C.parg[pb], am, __ATOMIC_RELAXED, __HIP_MEMORY_SCOPE_AGENT);
      }
    }
  }
}

__device__ __forceinline__ void merge_row(const Ctx& C, int row, int lane,
                                          float& m, float& s, int& am) {
  size_t b = (size_t)row * NVT;
  m = ld_coh(C.pmax + b + lane);
  s = ld_coh(C.psum + b + lane);
  am = __hip_atomic_load(&C.parg[b + lane], __ATOMIC_RELAXED, __HIP_MEMORY_SCOPE_AGENT);
  if (lane == 0) {
    float om = ld_coh(C.pmax + b + 64);
    float os = ld_coh(C.psum + b + 64);
    int oa = __hip_atomic_load(&C.parg[b + 64], __ATOMIC_RELAXED, __HIP_MEMORY_SCOPE_AGENT);
    combine3(m, s, am, om, os, oa);
  }
  #pragma unroll
  for (int msk = 32; msk; msk >>= 1) {
    float om = __shfl_xor(m, msk, 64);
    float os = __shfl_xor(s, msk, 64);
    int oa = __shfl_xor(am, msk, 64);
    combine3(m, s, am, om, os, oa);
  }
}

__global__ __launch_bounds__(NTHR) void decode_kernel(
    const float* enc, const float* emb, const float* Wih, const float* Whh,
    const float* bl, const float* Wpred, const float* bp, const float* Wjoin,
    const float* bj, const int* phon, float* out, float* wsf) {
  extern __shared__ float sm[];
  Ctx C;
  C.enc = enc; C.emb = emb; C.Wih = Wih; C.Whh = Whh; C.bl = bl;
  C.Wpred = Wpred; C.bp = bp; C.Wjoin = Wjoin; C.bj = bj; C.phon = phon;
  C.flags = (unsigned*)wsf;
  C.hx = (unsigned long long*)(wsf + WSF_HX);
  C.hhist = wsf + WSF_HHIST;
  C.preds = wsf + WSF_PREDS;
  C.pmax = wsf + WSF_PMAX;
  C.psum = wsf + WSF_PSUM;
  C.parg = (int*)(wsf + WSF_PARG);
  C.lse = wsf + WSF_LSE;
  C.out_align = out;
  C.out_pred  = out + (size_t)TT * VD;
  C.out_valid = out + (size_t)TT * VD + TT;

  const int tid = threadIdx.x;
  const int wid = tid >> 6, lane = tid & 63;
  unsigned ep = 1;

  // Phase 1: sequential predictor chain -> hhist
  chain_all(C, sm);
  heavy_barrier(C.flags);   // flush hhist plain stores
  // Phase 1b: batched pred projection
  preds_gemm(C, sm);
  heavy_barrier(C.flags);   // flush preds plain stores

  // Phase 2: speculative chunked decode
  int t = 0, tp = 0;
  while (t < TT && tp < NPH) {
    int K = CHUNK;
    if (TT - t < K) K = TT - t;
    if (NPH - tp < K) K = NPH - tp;
    joiner_gemm(C, sm, t, K, tp);
    light_barrier(C.flags, ep);

    int* amax_l = (int*)(sm + S_AMAX);
    for (int j = wid; j < K; j += 8) {
      float m, s; int am;
      merge_row(C, t + j, lane, m, s, am);
      if (lane == 0) {
        amax_l[j] = am;
        C.lse[t + j] = m + logf(s);
      }
    }
    __syncthreads();
    int cand = K;
    if (tid < K && amax_l[tid] == BLANK) cand = tid;
    #pragma unroll
    for (int msk = 32; msk; msk >>= 1) cand = min(cand, __shfl_xor(cand, msk, 64));
    int* red = (int*)(sm + S_RED);
    if (lane == 0) red[wid] = cand;
    __syncthreads();
    if (tid == 0) {
      int mn = red[0];
      for (int w2 = 1; w2 < 8; ++w2) mn = min(mn, red[w2]);
      red[8] = mn;
    }
    __syncthreads();
    int jb = red[8];
    __syncthreads();
    int nacc = (jb < K) ? jb + 1 : K;
    int nadv = (jb < K) ? jb : K;
    if (blockIdx.x == 0) {
      int* tok_sm = (int*)(sm + S_TOK);
      for (int j = tid; j < nacc; j += NTHR) {
        C.out_pred[t + j] = (j == jb) ? (float)BLANK : (float)tok_sm[tp + j + 2];
        C.out_valid[t + j] = 1.f;
      }
    }
    t += nacc; tp += nadv;
    if (jb < K) heavy_barrier(C.flags);   // rollback: flush dirty logits before rewrite
  }

  // Phase 3: forced-blank tail (pred = preds[NPH])
  if (t < TT) {
    int Kt = TT - t;
    joiner_gemm(C, sm, t, Kt, -1);
    light_barrier(C.flags, ep);
    for (int i = blockIdx.x * 8 + wid; i < Kt; i += NWG * 8) {
      float m, s; int am;
      merge_row(C, t + i, lane, m, s, am);
      if (lane == 0) C.lse[t + i] = m + logf(s);
    }
    const int gtid = blockIdx.x * NTHR + tid;
    for (int i = gtid; i < Kt; i += NWG * NTHR) {
      C.out_pred[t + i] = (float)BLANK;
      C.out_valid[t + i] = 0.f;
    }
  }

  heavy_barrier(C.flags);   // flush all logits + lse

  // Phase 4: logp = logits - lse (single streaming pass)
  for (int row = blockIdx.x; row < TT; row += NWG) {
    float l = C.lse[row];
    float* p = C.out_align + (size_t)row * VD;
    for (int i = tid; i < VD; i += NTHR) p[i] -= l;
  }
}

extern "C" void kernel_launch(void* const* d_in, const int* in_sizes, int n_in,
                              void* d_out, int out_size, void* d_ws, size_t ws_size,
                              hipStream_t stream) {
  const float* enc   = (const float*)d_in[0];
  const float* emb   = (const float*)d_in[1];
  const float* Wih   = (const float*)d_in[2];
  const float* Whh   = (const float*)d_in[3];
  const float* bl    = (const float*)d_in[4];
  const float* Wpred = (const float*)d_in[5];
  const float* bp    = (const float*)d_in[6];
  const float* Wjoin = (const float*)d_in[7];
  const float* bj    = (const float*)d_in[8];
  const int*   phon  = (const int*)d_in[9];
  float* out = (float*)d_out;
  float* wsf = (float*)d_ws;

  // flags + tagged h-exchange must start clean every call (ws poisoned once; stale
  // tags from a previous replay would alias step tags)
  hipMemsetAsync(d_ws, 0, MEMSET_BYTES, stream);
  hipFuncSetAttribute((const void*)decode_kernel,
                      hipFuncAttributeMaxDynamicSharedMemorySize, SMEM_BYTES);

  void* args[] = { &enc, &emb, &Wih, &Whh, &bl, &Wpred, &bp, &Wjoin, &bj, &phon, &out, &wsf };
  hipError_t e = hipLaunchCooperativeKernel((void*)decode_kernel, dim3(NWG), dim3(NTHR),
                                            args, SMEM_BYTES, stream);
  if (e != hipSuccess) {
    decode_kernel<<<dim3(NWG), dim3(NTHR), SMEM_BYTES, stream>>>(
        enc, emb, Wih, Whh, bl, Wpred, bp, Wjoin, bj, phon, out, wsf);
  }
}

// Round 4
// 2849.646 us; speedup vs baseline: 8.3459x; 1.5623x over previous
//
#include <hip/hip_runtime.h>
#include <math.h>

#define TT     4000
#define DENC   1024
#define HD     1024
#define DEMB   512
#define VD     8193
#define NPH    800
#define BLANK  8192
#define NWG    256
#define NTHR   512
#define CHUNK  256      // f32 fallback chunk
#define CHUNK_M 800     // mfma path speculative chunk
#define NSTEP  (NPH + 2)
#define NVT    65       // f32 path: v-tiles of 128
#define NP     129      // mfma path: v-blocks of 64

typedef __bf16 bf16x4 __attribute__((ext_vector_type(4)));
typedef __bf16 bf16x8 __attribute__((ext_vector_type(8)));
typedef float  f32x16 __attribute__((ext_vector_type(16)));

// ---- workspace layout (float offsets) ----
#define FLAGS_BYTES  4096
#define MEMSET_BYTES 20480
#define WSF_HX     1024                           // u64[2][1024]
#define WSF_HHIST  5120                           // NSTEP x 1024
#define WSF_PREDS  826368                         // (NPH+1) x 1024
// -- mfma layout --
#define WSF_PMAX_M 1646592                        // TT*NP
#define WSF_PSUM_M 2162592
#define WSF_PARG_M 2678592
#define WSF_LSE_M  3194592
#define WSF_AMAX_M 3198592                        // 1024 ints
#define WSF_W16    3199616                        // 8320*1024 bf16 = 4259840 floats
#define WSF_XBF    7459456                        // 3328*1024 bf16 = 1703936 floats
#define WSF_END_M  9163392
#define NEED_MFMA  ((size_t)WSF_END_M * 4)
// -- f32 fallback layout (round-3, proven) --
#define F_PMAX 1646592                            // TT*NVT
#define F_PSUM 1906592
#define F_PARG 2166592
#define F_LSE  2426592

// ---- LDS (floats) ----
#define S_XH   0
#define S_GS   3072
#define S_C4   3088
#define S_TOK  3264
#define S_RED  4066
#define S_AMAX 4082
#define SMEM_FLOATS_F32 4352
#define SMEM_BYTES_F32 (SMEM_FLOATS_F32 * 4)
// mfma kernel: GEMM dbuf [0,65536) bytes; red scratch @65536
#define SMEM_BYTES_MFMA (65536 + 128)

struct Ctx {
  const float *enc, *emb, *Wih, *Whh, *bl, *Wpred, *bp, *Wjoin, *bj;
  const int* phon;
  unsigned long long* hx;
  float *hhist, *preds, *pmax, *psum, *lse;
  int* parg;
  int* amaxws;
  __bf16 *w16, *xbf;
  unsigned* flags;
  float *out_align, *out_pred, *out_valid;
};

__device__ __forceinline__ float dot4(float4 a, float4 b, float acc) {
  acc = fmaf(a.x, b.x, acc); acc = fmaf(a.y, b.y, acc);
  acc = fmaf(a.z, b.z, acc); acc = fmaf(a.w, b.w, acc);
  return acc;
}
__device__ __forceinline__ float sigmf(float x) { return 1.f / (1.f + expf(-x)); }

// combine (max, sumexp, argmax); on ties keep smaller index (ref argmax = first max)
__device__ __forceinline__ void combine3(float& m, float& s, int& am,
                                         float om, float os, int oa) {
  float mm = fmaxf(m, om);
  s = s * __expf(m - mm) + os * __expf(om - mm);
  if (om > m || (om == m && oa < am)) am = oa;
  m = mm;
}

__device__ __forceinline__ void gload16(const void* g, void* l) {
  __builtin_amdgcn_global_load_lds(
      (const __attribute__((address_space(1))) unsigned int*)g,
      (__attribute__((address_space(3))) unsigned int*)l, 16, 0, 0);
}

// ---- light barrier: flag-array + release word, no cache flush (data via sc1 atomics)
__device__ __forceinline__ void light_barrier(unsigned* flags, unsigned& ep) {
  unsigned* arrive  = flags;
  unsigned* release = flags + 256;
  __builtin_amdgcn_s_waitcnt(0);
  __syncthreads();
  if (blockIdx.x == 0) {
    int tid = threadIdx.x;
    if (tid > 0 && tid < NWG) {
      while (__hip_atomic_load(&arrive[tid], __ATOMIC_RELAXED, __HIP_MEMORY_SCOPE_AGENT) != ep) {}
    }
    __syncthreads();
    if (tid == 0)
      __hip_atomic_store(release, ep, __ATOMIC_RELAXED, __HIP_MEMORY_SCOPE_AGENT);
  } else {
    if (threadIdx.x == 0) {
      __hip_atomic_store(&arrive[blockIdx.x], ep, __ATOMIC_RELAXED, __HIP_MEMORY_SCOPE_AGENT);
      while (__hip_atomic_load(release, __ATOMIC_RELAXED, __HIP_MEMORY_SCOPE_AGENT) != ep) {}
    }
    __syncthreads();
  }
  asm volatile("" ::: "memory");
  ep++;
}

// ---- heavy barrier: full fence (wbl2+inv) for plain-store handoffs
__device__ __forceinline__ void heavy_barrier(unsigned* flags) {
  unsigned* bar = flags + 257;
  __syncthreads();
  if (threadIdx.x == 0) {
    __threadfence();
    unsigned g = __hip_atomic_load(&bar[1], __ATOMIC_RELAXED, __HIP_MEMORY_SCOPE_AGENT);
    unsigned v = __hip_atomic_fetch_add(&bar[0], 1u, __ATOMIC_RELAXED, __HIP_MEMORY_SCOPE_AGENT);
    if (v == (unsigned)(NWG - 1)) {
      __hip_atomic_store(&bar[0], 0u, __ATOMIC_RELAXED, __HIP_MEMORY_SCOPE_AGENT);
      __hip_atomic_store(&bar[1], g + 1u, __ATOMIC_RELEASE, __HIP_MEMORY_SCOPE_AGENT);
    } else {
      while (__hip_atomic_load(&bar[1], __ATOMIC_RELAXED, __HIP_MEMORY_SCOPE_AGENT) == g)
        __builtin_amdgcn_s_sleep(1);
    }
    __threadfence();
  }
  __syncthreads();
}

__device__ __forceinline__ float ld_coh(const float* p) {
  return __hip_atomic_load((const float*)p, __ATOMIC_RELAXED, __HIP_MEMORY_SCOPE_AGENT);
}

// ---- Phase 1: 802 sequential LSTM steps (unchanged from round 3)
__device__ void chain_all(const Ctx& C, float* sm) {
  const int tid = threadIdx.x;
  const int w = tid >> 6, l = tid & 63;
  const int b = blockIdx.x;
  int* tok_sm = (int*)(sm + S_TOK);

  for (int s = tid; s < NSTEP; s += NTHR)
    tok_sm[s] = (s < 2) ? BLANK : C.phon[s - 2];

  float4 W0[6], W1[6];
  {
    int rr0 = 2 * w, rr1 = 2 * w + 1;
    int gr0 = ((rr0 >> 2) << 10) + 4 * b + (rr0 & 3);
    int gr1 = ((rr1 >> 2) << 10) + 4 * b + (rr1 & 3);
    const float4* ih0 = (const float4*)(C.Wih + (size_t)gr0 * DEMB);
    const float4* hh0 = (const float4*)(C.Whh + (size_t)gr0 * HD);
    const float4* ih1 = (const float4*)(C.Wih + (size_t)gr1 * DEMB);
    const float4* hh1 = (const float4*)(C.Whh + (size_t)gr1 * HD);
    W0[0] = ih0[l];       W0[1] = ih0[64 + l];
    W0[2] = hh0[l];       W0[3] = hh0[64 + l];
    W0[4] = hh0[128 + l]; W0[5] = hh0[192 + l];
    W1[0] = ih1[l];       W1[1] = ih1[64 + l];
    W1[2] = hh1[l];       W1[3] = hh1[64 + l];
    W1[4] = hh1[128 + l]; W1[5] = hh1[192 + l];
  }
  float bi = 0.f, bf = 0.f, bg = 0.f, bo = 0.f;
  if (tid < 4) {
    bi = C.bl[4 * b + tid];
    bf = C.bl[1024 + 4 * b + tid];
    bg = C.bl[2048 + 4 * b + tid];
    bo = C.bl[3072 + 4 * b + tid];
    sm[S_C4 + tid] = 0.f;
  }
  for (int i = tid; i < 1536; i += NTHR) sm[S_XH + i] = 0.f;
  if (tid < 512) sm[S_XH + tid] = C.emb[(size_t)BLANK * DEMB + tid];
  __syncthreads();

  unsigned long long* hx = C.hx;
  for (int s = 0; s < NSTEP; ++s) {
    int p = s & 1;
    const float4* xh4 = (const float4*)(sm + S_XH + p * 1536);
    float a0 = 0.f, a1 = 0.f;
    #pragma unroll
    for (int i = 0; i < 6; ++i) {
      float4 v = xh4[i * 64 + l];
      a0 = dot4(W0[i], v, a0);
      a1 = dot4(W1[i], v, a1);
    }
    #pragma unroll
    for (int m = 32; m; m >>= 1) {
      a0 += __shfl_xor(a0, m, 64);
      a1 += __shfl_xor(a1, m, 64);
    }
    if (l == 0) { sm[S_GS + 2 * w] = a0; sm[S_GS + 2 * w + 1] = a1; }
    if (s + 1 < NSTEP && tid < 512)
      sm[S_XH + (1 - p) * 1536 + tid] = C.emb[(size_t)tok_sm[s + 1] * DEMB + tid];
    __syncthreads();
    if (tid < 4) {
      int j = tid;
      float gi = sm[S_GS + j]      + bi;
      float gf = sm[S_GS + 4 + j]  + bf;
      float gg = sm[S_GS + 8 + j]  + bg;
      float go = sm[S_GS + 12 + j] + bo;
      float cc = sm[S_C4 + j];
      float c2 = sigmf(gf) * cc + sigmf(gi) * tanhf(gg);
      float h2 = sigmf(go) * tanhf(c2);
      sm[S_C4 + j] = c2;
      int cell = 4 * b + j;
      C.hhist[(size_t)s * HD + cell] = h2;
      unsigned long long pk = ((unsigned long long)(unsigned)(s + 1) << 32)
                            | (unsigned long long)__float_as_uint(h2);
      __hip_atomic_store(&hx[(1 - p) * 1024 + cell], pk,
                         __ATOMIC_RELAXED, __HIP_MEMORY_SCOPE_AGENT);
    }
    if (s + 1 < NSTEP) {
      unsigned tg = (unsigned)(s + 1);
      #pragma unroll
      for (int kq = 0; kq < 2; ++kq) {
        int k = tid + kq * 512;
        unsigned long long v;
        do {
          v = __hip_atomic_load(&hx[(1 - p) * 1024 + k],
                                __ATOMIC_RELAXED, __HIP_MEMORY_SCOPE_AGENT);
        } while ((unsigned)(v >> 32) != tg);
        sm[S_XH + (1 - p) * 1536 + 512 + k] = __uint_as_float((unsigned)v);
      }
    }
    __syncthreads();
  }
}

// ---- Phase 1b: preds[i] = W_pred @ hhist[i+1] + bp (f32 tiled GEMM, unchanged)
__device__ void preds_gemm(const Ctx& C, float* sm) {
  float* Wt = sm;
  float* Xt = sm + 2112;
  const int tid = threadIdx.x;
  const int tx = tid & 31, ty = tid >> 5;
  const int NJT = (NPH + 1 + 63) >> 6;
  int ntiles = 8 * NJT;
  for (int tile = blockIdx.x; tile < ntiles; tile += NWG) {
    int vt = tile & 7, jt = tile >> 3;
    int v0 = vt * 128, j0 = jt * 64;
    float acc[4][4];
    #pragma unroll
    for (int a = 0; a < 4; ++a)
      #pragma unroll
      for (int q = 0; q < 4; ++q) acc[a][q] = 0.f;
    for (int kk = 0; kk < 1024; kk += 16) {
      {
        int r = tid >> 2, seg = tid & 3;
        float4 wv = ((const float4*)(C.Wpred + (size_t)(v0 + r) * HD + kk))[seg];
        Wt[(seg * 4 + 0) * 132 + r] = wv.x;
        Wt[(seg * 4 + 1) * 132 + r] = wv.y;
        Wt[(seg * 4 + 2) * 132 + r] = wv.z;
        Wt[(seg * 4 + 3) * 132 + r] = wv.w;
      }
      if (tid < 256) {
        int r = tid >> 2, seg = tid & 3;
        int j = j0 + r;
        float4 xv = make_float4(0.f, 0.f, 0.f, 0.f);
        if (j <= NPH) xv = ((const float4*)(C.hhist + (size_t)(j + 1) * HD + kk))[seg];
        Xt[(seg * 4 + 0) * 68 + r] = xv.x;
        Xt[(seg * 4 + 1) * 68 + r] = xv.y;
        Xt[(seg * 4 + 2) * 68 + r] = xv.z;
        Xt[(seg * 4 + 3) * 68 + r] = xv.w;
      }
      __syncthreads();
      #pragma unroll
      for (int k = 0; k < 16; ++k) {
        float4 a = *(const float4*)(Wt + k * 132 + (tx << 2));
        float4 bq = *(const float4*)(Xt + k * 68 + (ty << 2));
        acc[0][0] = fmaf(a.x, bq.x, acc[0][0]); acc[1][0] = fmaf(a.y, bq.x, acc[1][0]);
        acc[2][0] = fmaf(a.z, bq.x, acc[2][0]); acc[3][0] = fmaf(a.w, bq.x, acc[3][0]);
        acc[0][1] = fmaf(a.x, bq.y, acc[0][1]); acc[1][1] = fmaf(a.y, bq.y, acc[1][1]);
        acc[2][1] = fmaf(a.z, bq.y, acc[2][1]); acc[3][1] = fmaf(a.w, bq.y, acc[3][1]);
        acc[0][2] = fmaf(a.x, bq.z, acc[0][2]); acc[1][2] = fmaf(a.y, bq.z, acc[1][2]);
        acc[2][2] = fmaf(a.z, bq.z, acc[2][2]); acc[3][2] = fmaf(a.w, bq.z, acc[3][2]);
        acc[0][3] = fmaf(a.x, bq.w, acc[0][3]); acc[1][3] = fmaf(a.y, bq.w, acc[1][3]);
        acc[2][3] = fmaf(a.z, bq.w, acc[2][3]); acc[3][3] = fmaf(a.w, bq.w, acc[3][3]);
      }
      __syncthreads();
    }
    int vb = v0 + (tx << 2), jb0 = j0 + (ty << 2);
    #pragma unroll
    for (int jj = 0; jj < 4; ++jj) {
      int j = jb0 + jj;
      if (j > NPH) continue;
      #pragma unroll
      for (int q = 0; q < 4; ++q)
        C.preds[(size_t)j * 1024 + vb + q] = acc[q][jj] + C.bp[vb + q];
    }
  }
}

// ================= MFMA joiner path =================

// Xbf[j] = bf16(relu(enc[t0+j] + preds[pi])), j in [0,K)
__device__ void xbf_pass(const Ctx& C, int t0, int K, int pi0) {
  int g0 = blockIdx.x * NTHR + threadIdx.x;
  int total = K << 8;
  for (int q = g0; q < total; q += NWG * NTHR) {
    int j = q >> 8, seg = q & 255;
    int pi = (pi0 < 0) ? NPH : pi0 + j;
    float4 e = ((const float4*)(C.enc + (size_t)(t0 + j) * 1024))[seg];
    float4 p = ((const float4*)(C.preds + (size_t)pi * 1024))[seg];
    bf16x4 r;
    r[0] = (__bf16)fmaxf(e.x + p.x, 0.f);
    r[1] = (__bf16)fmaxf(e.y + p.y, 0.f);
    r[2] = (__bf16)fmaxf(e.z + p.z, 0.f);
    r[3] = (__bf16)fmaxf(e.w + p.w, 0.f);
    *(bf16x4*)(C.xbf + (size_t)j * 1024 + (seg << 2)) = r;
  }
}

// 128v x 128j tiles, 8 waves (wj 0..3, wv 0..1), mfma_f32_32x32x16_bf16,
// C[j][v] (A = X, B = W^T) so v = lane&31 -> coalesced stores.
// LDS: k-major [ks][row] 16B chunks, double-buffered, staged via global_load_lds.
__device__ void joiner_mfma(const Ctx& C, char* smc, int t0, int K) {
  const int tid = threadIdx.x;
  const int wid = tid >> 6, lane = tid & 63;
  const int wj = wid & 3, wv = wid >> 2;
  const int l31 = lane & 31, lhi = lane >> 5;
  const int jt_n = (K + 127) >> 7;
  const int ntiles = jt_n * NVT;
  const __bf16* W16 = C.w16;
  const __bf16* Xbf = C.xbf;

  for (int tile = blockIdx.x; tile < ntiles; tile += NWG) {
    const int vt = tile % NVT, jt = tile / NVT;
    const int v0 = vt << 7, j0 = jt << 7;
    f32x16 acc0, acc1;
    #pragma unroll
    for (int i = 0; i < 16; ++i) { acc0[i] = 0.f; acc1[i] = 0.f; }

    // staging: slot s in [0,1024): ks = s>>7, row = s&127; LDS chunk = slot*16B
    auto stage = [&](int db, int kb) {
      char* wb = smc + db * 32768;
      char* xb = wb + 16384;
      #pragma unroll
      for (int p = 0; p < 2; ++p) {
        int sbase = p * 512 + wid * 64;      // wave-uniform LDS base
        int s = sbase + lane;
        int ks = s >> 7, r = s & 127;
        gload16(W16 + (size_t)(v0 + r) * 1024 + kb + ks * 8, wb + sbase * 16);
        gload16(Xbf + (size_t)(j0 + r) * 1024 + kb + ks * 8, xb + sbase * 16);
      }
    };

    stage(0, 0);
    __syncthreads();
    int db = 0;
    for (int kb16 = 0; kb16 < 16; ++kb16) {
      if (kb16 < 15) stage(db ^ 1, (kb16 + 1) << 6);
      const char* wb = smc + db * 32768;
      const char* xb = wb + 16384;
      #pragma unroll
      for (int k16 = 0; k16 < 4; ++k16) {
        int ks = k16 * 2 + lhi;
        bf16x8 a  = *(const bf16x8*)(xb + ((ks << 7) + (wj << 5) + l31) * 16);
        bf16x8 b0 = *(const bf16x8*)(wb + ((ks << 7) + (wv << 6) + l31) * 16);
        bf16x8 b1 = *(const bf16x8*)(wb + ((ks << 7) + (wv << 6) + 32 + l31) * 16);
        acc0 = __builtin_amdgcn_mfma_f32_32x32x16_bf16(a, b0, acc0, 0, 0, 0);
        acc1 = __builtin_amdgcn_mfma_f32_32x32x16_bf16(a, b1, acc1, 0, 0, 0);
      }
      __syncthreads();
      db ^= 1;
    }

    // epilogue: logits + per-(row, v64) softmax partials
    const int v_0 = v0 + (wv << 6) + l31;
    const int v_1 = v_0 + 32;
    const float bj0 = (v_0 < VD) ? C.bj[v_0] : 0.f;
    const float bj1 = (v_1 < VD) ? C.bj[v_1] : 0.f;
    const int jbase = j0 + (wj << 5) + 4 * lhi;
    const bool npok = (v0 + (wv << 6)) < VD;
    const int np = (v0 >> 6) + wv;
    #pragma unroll
    for (int reg = 0; reg < 16; ++reg) {
      int j = jbase + (reg & 3) + 8 * (reg >> 2);
      bool jok = j < K;
      float lg0 = acc0[reg] + bj0;
      float lg1 = acc1[reg] + bj1;
      if (jok) {
        size_t ro = (size_t)(t0 + j) * VD;
        if (v_0 < VD) C.out_align[ro + v_0] = lg0;
        if (v_1 < VD) C.out_align[ro + v_1] = lg1;
      }
      float l0 = (v_0 < VD) ? lg0 : -1e30f;
      float l1 = (v_1 < VD) ? lg1 : -1e30f;
      float m = fmaxf(l0, l1);
      float ss = 0.f;
      if (v_0 < VD) ss += __expf(l0 - m);
      if (v_1 < VD) ss += __expf(l1 - m);
      int am = (l1 > l0) ? v_1 : v_0;
      #pragma unroll
      for (int msk = 1; msk <= 16; msk <<= 1) {
        float om = __shfl_xor(m, msk, 64);
        float os = __shfl_xor(ss, msk, 64);
        int oa = __shfl_xor(am, msk, 64);
        float mm = fmaxf(m, om);
        ss = ss * __expf(m - mm) + os * __expf(om - mm);
        if (om > m || (om == m && oa < am)) am = oa;
        m = mm;
      }
      if (l31 == 0 && jok && npok) {
        size_t pb = (size_t)(t0 + j) * NP + np;
        __hip_atomic_store(&C.pmax[pb], m, __ATOMIC_RELAXED, __HIP_MEMORY_SCOPE_AGENT);
        __hip_atomic_store(&C.psum[pb], ss, __ATOMIC_RELAXED, __HIP_MEMORY_SCOPE_AGENT);
        __hip_atomic_store(&C.parg[pb], am, __ATOMIC_RELAXED, __HIP_MEMORY_SCOPE_AGENT);
      }
    }
  }
}

__device__ __forceinline__ void merge_row129(const Ctx& C, int row, int lane,
                                             float& m, float& s, int& am) {
  size_t b = (size_t)row * NP;
  m = ld_coh(C.pmax + b + lane);
  s = ld_coh(C.psum + b + lane);
  am = __hip_atomic_load(&C.parg[b + lane], __ATOMIC_RELAXED, __HIP_MEMORY_SCOPE_AGENT);
  {
    int i2 = lane + 64;   // 64..127
    float om = ld_coh(C.pmax + b + i2);
    float os = ld_coh(C.psum + b + i2);
    int oa = __hip_atomic_load(&C.parg[b + i2], __ATOMIC_RELAXED, __HIP_MEMORY_SCOPE_AGENT);
    combine3(m, s, am, om, os, oa);
  }
  if (lane == 0) {
    float om = ld_coh(C.pmax + b + 128);
    float os = ld_coh(C.psum + b + 128);
    int oa = __hip_atomic_load(&C.parg[b + 128], __ATOMIC_RELAXED, __HIP_MEMORY_SCOPE_AGENT);
    combine3(m, s, am, om, os, oa);
  }
  #pragma unroll
  for (int msk = 32; msk; msk >>= 1) {
    float om = __shfl_xor(m, msk, 64);
    float os = __shfl_xor(s, msk, 64);
    int oa = __shfl_xor(am, msk, 64);
    combine3(m, s, am, om, os, oa);
  }
}

__global__ __launch_bounds__(NTHR) void decode_kernel_mfma(
    const float* enc, const float* emb, const float* Wih, const float* Whh,
    const float* bl, const float* Wpred, const float* bp, const float* Wjoin,
    const float* bj, const int* phon, float* out, float* wsf) {
  extern __shared__ float sm[];
  char* smc = (char*)sm;
  Ctx C;
  C.enc = enc; C.emb = emb; C.Wih = Wih; C.Whh = Whh; C.bl = bl;
  C.Wpred = Wpred; C.bp = bp; C.Wjoin = Wjoin; C.bj = bj; C.phon = phon;
  C.flags = (unsigned*)wsf;
  C.hx = (unsigned long long*)(wsf + WSF_HX);
  C.hhist = wsf + WSF_HHIST;
  C.preds = wsf + WSF_PREDS;
  C.pmax = wsf + WSF_PMAX_M;
  C.psum = wsf + WSF_PSUM_M;
  C.parg = (int*)(wsf + WSF_PARG_M);
  C.lse = wsf + WSF_LSE_M;
  C.amaxws = (int*)(wsf + WSF_AMAX_M);
  C.w16 = (__bf16*)(wsf + WSF_W16);
  C.xbf = (__bf16*)(wsf + WSF_XBF);
  C.out_align = out;
  C.out_pred  = out + (size_t)TT * VD;
  C.out_valid = out + (size_t)TT * VD + TT;

  const int tid = threadIdx.x;
  const int wid = tid >> 6, lane = tid & 63;
  unsigned ep = 1;

  // Phase 0: W_join -> bf16 (padded rows read-garbage-safe)
  {
    int g0 = blockIdx.x * NTHR + tid;
    for (int q = g0; q < VD * 256; q += NWG * NTHR) {
      int v = q >> 8, seg = q & 255;
      float4 w4 = ((const float4*)(C.Wjoin + (size_t)v * 1024))[seg];
      bf16x4 r;
      r[0] = (__bf16)w4.x; r[1] = (__bf16)w4.y; r[2] = (__bf16)w4.z; r[3] = (__bf16)w4.w;
      *(bf16x4*)(C.w16 + (size_t)v * 1024 + (seg << 2)) = r;
    }
  }

  // Phase 1: sequential predictor chain
  chain_all(C, sm);
  heavy_barrier(C.flags);
  preds_gemm(C, sm);
  heavy_barrier(C.flags);   // flush preds + W16

  int t = 0, tp = 0;
  while (t < TT && tp < NPH) {
    int K = CHUNK_M;
    if (TT - t < K) K = TT - t;
    if (NPH - tp < K) K = NPH - tp;
    heavy_barrier(C.flags);          // safe rewrite of Xbf/logits (first iter: extra)
    xbf_pass(C, t, K, tp);
    heavy_barrier(C.flags);
    joiner_mfma(C, smc, t, K);
    light_barrier(C.flags, ep);

    // distributed merge: one row per wave
    for (int j = blockIdx.x * 8 + wid; j < K; j += NWG * 8) {
      float m, s; int am;
      merge_row129(C, t + j, lane, m, s, am);
      if (lane == 0) {
        __hip_atomic_store(&C.amaxws[j], am, __ATOMIC_RELAXED, __HIP_MEMORY_SCOPE_AGENT);
        C.lse[t + j] = m + logf(s);
      }
    }
    light_barrier(C.flags, ep);

    // decision: first blank (redundant per WG -> uniform)
    int cand = K;
    for (int idx = tid; idx < K; idx += NTHR) {
      int a = __hip_atomic_load(&C.amaxws[idx], __ATOMIC_RELAXED, __HIP_MEMORY_SCOPE_AGENT);
      if (a == BLANK && idx < cand) cand = idx;
    }
    #pragma unroll
    for (int msk = 32; msk; msk >>= 1) cand = min(cand, __shfl_xor(cand, msk, 64));
    int* red = (int*)(smc + 65536);
    if (lane == 0) red[wid] = cand;
    __syncthreads();
    if (tid == 0) {
      int mn = red[0];
      for (int w2 = 1; w2 < 8; ++w2) mn = min(mn, red[w2]);
      red[8] = mn;
    }
    __syncthreads();
    int jb = red[8];
    __syncthreads();
    int nacc = (jb < K) ? jb + 1 : K;
    int nadv = (jb < K) ? jb : K;
    if (blockIdx.x == 0) {
      for (int j = tid; j < nacc; j += NTHR) {
        C.out_pred[t + j] = (j == jb) ? (float)BLANK : (float)C.phon[tp + j];
        C.out_valid[t + j] = 1.f;
      }
    }
    t += nacc; tp += nadv;
  }

  // tail: forced blank, pred = preds[NPH]
  if (t < TT) {
    int Kt = TT - t;
    heavy_barrier(C.flags);
    xbf_pass(C, t, Kt, -1);
    heavy_barrier(C.flags);
    joiner_mfma(C, smc, t, Kt);
    light_barrier(C.flags, ep);
    for (int j = blockIdx.x * 8 + wid; j < Kt; j += NWG * 8) {
      float m, s; int am;
      merge_row129(C, t + j, lane, m, s, am);
      if (lane == 0) C.lse[t + j] = m + logf(s);
    }
    const int gtid = blockIdx.x * NTHR + tid;
    for (int i = gtid; i < Kt; i += NWG * NTHR) {
      C.out_pred[t + i] = (float)BLANK;
      C.out_valid[t + i] = 0.f;
    }
  }

  heavy_barrier(C.flags);

  // Phase 4: logp = logits - lse
  for (int row = blockIdx.x; row < TT; row += NWG) {
    float l = C.lse[row];
    float* p = C.out_align + (size_t)row * VD;
    for (int i = tid; i < VD; i += NTHR) p[i] -= l;
  }
}

// ================= f32 fallback (round-3, proven) =================

__device__ void joiner_gemm_f32(const Ctx& C, float* sm, int t0, int K, int pi0) {
  float* Wt = sm;
  float* Xt = sm + 2112;
  const int tid = threadIdx.x;
  const int tx = tid & 31, ty = tid >> 5;
  int jt_n = (K + 63) >> 6;
  int ntiles = jt_n * NVT;
  for (int tile = blockIdx.x; tile < ntiles; tile += NWG) {
    int vt = tile % NVT, jt = tile / NVT;
    int v0 = vt * 128, j0 = jt * 64;
    float acc[4][4];
    #pragma unroll
    for (int a = 0; a < 4; ++a)
      #pragma unroll
      for (int q = 0; q < 4; ++q) acc[a][q] = 0.f;

    for (int kk = 0; kk < 1024; kk += 16) {
      {
        int r = tid >> 2, seg = tid & 3;
        int v = v0 + r;
        float4 wv = make_float4(0.f, 0.f, 0.f, 0.f);
        if (v < VD) wv = ((const float4*)(C.Wjoin + (size_t)v * 1024 + kk))[seg];
        Wt[(seg * 4 + 0) * 132 + r] = wv.x;
        Wt[(seg * 4 + 1) * 132 + r] = wv.y;
        Wt[(seg * 4 + 2) * 132 + r] = wv.z;
        Wt[(seg * 4 + 3) * 132 + r] = wv.w;
      }
      if (tid < 256) {
        int r = tid >> 2, seg = tid & 3;
        int j = j0 + r;
        float4 xv = make_float4(0.f, 0.f, 0.f, 0.f);
        if (j < K) {
          int pi = (pi0 < 0) ? NPH : (pi0 + j);
          float4 e = ((const float4*)(C.enc + (size_t)(t0 + j) * DENC + kk))[seg];
          float4 pr = ((const float4*)(C.preds + (size_t)pi * 1024 + kk))[seg];
          xv.x = fmaxf(e.x + pr.x, 0.f);
          xv.y = fmaxf(e.y + pr.y, 0.f);
          xv.z = fmaxf(e.z + pr.z, 0.f);
          xv.w = fmaxf(e.w + pr.w, 0.f);
        }
        Xt[(seg * 4 + 0) * 68 + r] = xv.x;
        Xt[(seg * 4 + 1) * 68 + r] = xv.y;
        Xt[(seg * 4 + 2) * 68 + r] = xv.z;
        Xt[(seg * 4 + 3) * 68 + r] = xv.w;
      }
      __syncthreads();
      #pragma unroll
      for (int k = 0; k < 16; ++k) {
        float4 a = *(const float4*)(Wt + k * 132 + (tx << 2));
        float4 bq = *(const float4*)(Xt + k * 68 + (ty << 2));
        acc[0][0] = fmaf(a.x, bq.x, acc[0][0]); acc[1][0] = fmaf(a.y, bq.x, acc[1][0]);
        acc[2][0] = fmaf(a.z, bq.x, acc[2][0]); acc[3][0] = fmaf(a.w, bq.x, acc[3][0]);
        acc[0][1] = fmaf(a.x, bq.y, acc[0][1]); acc[1][1] = fmaf(a.y, bq.y, acc[1][1]);
        acc[2][1] = fmaf(a.z, bq.y, acc[2][1]); acc[3][1] = fmaf(a.w, bq.y, acc[3][1]);
        acc[0][2] = fmaf(a.x, bq.z, acc[0][2]); acc[1][2] = fmaf(a.y, bq.z, acc[1][2]);
        acc[2][2] = fmaf(a.z, bq.z, acc[2][2]); acc[3][2] = fmaf(a.w, bq.z, acc[3][2]);
        acc[0][3] = fmaf(a.x, bq.w, acc[0][3]); acc[1][3] = fmaf(a.y, bq.w, acc[1][3]);
        acc[2][3] = fmaf(a.z, bq.w, acc[2][3]); acc[3][3] = fmaf(a.w, bq.w, acc[3][3]);
      }
      __syncthreads();
    }
    int vb = v0 + (tx << 2);
    int jb0 = j0 + (ty << 2);
    float bjv[4];
    #pragma unroll
    for (int q = 0; q < 4; ++q) bjv[q] = (vb + q < VD) ? C.bj[vb + q] : 0.f;
    #pragma unroll
    for (int jj = 0; jj < 4; ++jj) {
      int j = jb0 + jj;
      if (j >= K) continue;
      size_t ro = (size_t)(t0 + j) * VD;
      float lg[4];
      float m = -1e30f; int am = vb;
      #pragma unroll
      for (int q = 0; q < 4; ++q) {
        int v = vb + q;
        if (v < VD) {
          lg[q] = acc[q][jj] + bjv[q];
          C.out_align[ro + v] = lg[q];
          if (lg[q] > m) { m = lg[q]; am = v; }
        } else lg[q] = -1e30f;
      }
      float ss = 0.f;
      #pragma unroll
      for (int q = 0; q < 4; ++q)
        if (vb + q < VD) ss += __expf(lg[q] - m);
      #pragma unroll
      for (int msk = 16; msk; msk >>= 1) {
        float om = __shfl_xor(m, msk, 64);
        float os = __shfl_xor(ss, msk, 64);
        int oa = __shfl_xor(am, msk, 64);
        combine3(m, ss, am, om, os, oa);
      }
      if (tx == 0) {
        size_t pb = (size_t)(t0 + j) * NVT + vt;
        __hip_atomic_store(&C.pmax[pb], m, __ATOMIC_RELAXED, __HIP_MEMORY_SCOPE_AGENT);
        __hip_atomic_store(&C.psum[pb], ss, __ATOMIC_RELAXED, __HIP_MEMORY_SCOPE_AGENT);
        __hip_atomic_store(&C.parg[pb], am, __ATOMIC_RELAXED, __HIP_MEMORY_SCOPE_AGENT);
      }
    }
  }
}

__device__ __forceinline__ void merge_row65(const Ctx& C, int row, int lane,
                                            float& m, float& s, int& am) {
  size_t b = (size_t)row * NVT;
  m = ld_coh(C.pmax + b + lane);
  s = ld_coh(C.psum + b + lane);
  am = __hip_atomic_load(&C.parg[b + lane], __ATOMIC_RELAXED, __HIP_MEMORY_SCOPE_AGENT);
  if (lane == 0) {
    float om = ld_coh(C.pmax + b + 64);
    float os = ld_coh(C.psum + b + 64);
    int oa = __hip_atomic_load(&C.parg[b + 64], __ATOMIC_RELAXED, __HIP_MEMORY_SCOPE_AGENT);
    combine3(m, s, am, om, os, oa);
  }
  #pragma unroll
  for (int msk = 32; msk; msk >>= 1) {
    float om = __shfl_xor(m, msk, 64);
    float os = __shfl_xor(s, msk, 64);
    int oa = __shfl_xor(am, msk, 64);
    combine3(m, s, am, om, os, oa);
  }
}

__global__ __launch_bounds__(NTHR) void decode_kernel_f32(
    const float* enc, const float* emb, const float* Wih, const float* Whh,
    const float* bl, const float* Wpred, const float* bp, const float* Wjoin,
    const float* bj, const int* phon, float* out, float* wsf) {
  extern __shared__ float sm[];
  Ctx C;
  C.enc = enc; C.emb = emb; C.Wih = Wih; C.Whh = Whh; C.bl = bl;
  C.Wpred = Wpred; C.bp = bp; C.Wjoin = Wjoin; C.bj = bj; C.phon = phon;
  C.flags = (unsigned*)wsf;
  C.hx = (unsigned long long*)(wsf + WSF_HX);
  C.hhist = wsf + WSF_HHIST;
  C.preds = wsf + WSF_PREDS;
  C.pmax = wsf + F_PMAX;
  C.psum = wsf + F_PSUM;
  C.parg = (int*)(wsf + F_PARG);
  C.lse = wsf + F_LSE;
  C.amaxws = 0; C.w16 = 0; C.xbf = 0;
  C.out_align = out;
  C.out_pred  = out + (size_t)TT * VD;
  C.out_valid = out + (size_t)TT * VD + TT;

  const int tid = threadIdx.x;
  const int wid = tid >> 6, lane = tid & 63;
  unsigned ep = 1;

  chain_all(C, sm);
  heavy_barrier(C.flags);
  preds_gemm(C, sm);
  heavy_barrier(C.flags);

  int t = 0, tp = 0;
  while (t < TT && tp < NPH) {
    int K = CHUNK;
    if (TT - t < K) K = TT - t;
    if (NPH - tp < K) K = NPH - tp;
    joiner_gemm_f32(C, sm, t, K, tp);
    light_barrier(C.flags, ep);

    int* amax_l = (int*)(sm + S_AMAX);
    for (int j = wid; j < K; j += 8) {
      float m, s; int am;
      merge_row65(C, t + j, lane, m, s, am);
      if (lane == 0) {
        amax_l[j] = am;
        C.lse[t + j] = m + logf(s);
      }
    }
    __syncthreads();
    int cand = K;
    if (tid < K && amax_l[tid] == BLANK) cand = tid;
    #pragma unroll
    for (int msk = 32; msk; msk >>= 1) cand = min(cand, __shfl_xor(cand, msk, 64));
    int* red = (int*)(sm + S_RED);
    if (lane == 0) red[wid] = cand;
    __syncthreads();
    if (tid == 0) {
      int mn = red[0];
      for (int w2 = 1; w2 < 8; ++w2) mn = min(mn, red[w2]);
      red[8] = mn;
    }
    __syncthreads();
    int jb = red[8];
    __syncthreads();
    int nacc = (jb < K) ? jb + 1 : K;
    int nadv = (jb < K) ? jb : K;
    if (blockIdx.x == 0) {
      int* tok_sm = (int*)(sm + S_TOK);
      for (int j = tid; j < nacc; j += NTHR) {
        C.out_pred[t + j] = (j == jb) ? (float)BLANK : (float)tok_sm[tp + j + 2];
        C.out_valid[t + j] = 1.f;
      }
    }
    t += nacc; tp += nadv;
    if (jb < K) heavy_barrier(C.flags);
  }

  if (t < TT) {
    int Kt = TT - t;
    joiner_gemm_f32(C, sm, t, Kt, -1);
    light_barrier(C.flags, ep);
    for (int i = blockIdx.x * 8 + wid; i < Kt; i += NWG * 8) {
      float m, s; int am;
      merge_row65(C, t + i, lane, m, s, am);
      if (lane == 0) C.lse[t + i] = m + logf(s);
    }
    const int gtid = blockIdx.x * NTHR + tid;
    for (int i = gtid; i < Kt; i += NWG * NTHR) {
      C.out_pred[t + i] = (float)BLANK;
      C.out_valid[t + i] = 0.f;
    }
  }

  heavy_barrier(C.flags);

  for (int row = blockIdx.x; row < TT; row += NWG) {
    float l = C.lse[row];
    float* p = C.out_align + (size_t)row * VD;
    for (int i = tid; i < VD; i += NTHR) p[i] -= l;
  }
}

extern "C" void kernel_launch(void* const* d_in, const int* in_sizes, int n_in,
                              void* d_out, int out_size, void* d_ws, size_t ws_size,
                              hipStream_t stream) {
  const float* enc   = (const float*)d_in[0];
  const float* emb   = (const float*)d_in[1];
  const float* Wih   = (const float*)d_in[2];
  const float* Whh   = (const float*)d_in[3];
  const float* bl    = (const float*)d_in[4];
  const float* Wpred = (const float*)d_in[5];
  const float* bp    = (const float*)d_in[6];
  const float* Wjoin = (const float*)d_in[7];
  const float* bj    = (const float*)d_in[8];
  const int*   phon  = (const int*)d_in[9];
  float* out = (float*)d_out;
  float* wsf = (float*)d_ws;

  hipMemsetAsync(d_ws, 0, MEMSET_BYTES, stream);

  void* args[] = { &enc, &emb, &Wih, &Whh, &bl, &Wpred, &bp, &Wjoin, &bj, &phon, &out, &wsf };
  if (ws_size >= NEED_MFMA) {
    hipFuncSetAttribute((const void*)decode_kernel_mfma,
                        hipFuncAttributeMaxDynamicSharedMemorySize, SMEM_BYTES_MFMA);
    hipError_t e = hipLaunchCooperativeKernel((void*)decode_kernel_mfma, dim3(NWG), dim3(NTHR),
                                              args, SMEM_BYTES_MFMA, stream);
    if (e != hipSuccess) {
      decode_kernel_mfma<<<dim3(NWG), dim3(NTHR), SMEM_BYTES_MFMA, stream>>>(
          enc, emb, Wih, Whh, bl, Wpred, bp, Wjoin, bj, phon, out, wsf);
    }
  } else {
    hipFuncSetAttribute((const void*)decode_kernel_f32,
                        hipFuncAttributeMaxDynamicSharedMemorySize, SMEM_BYTES_F32);
    hipError_t e = hipLaunchCooperativeKernel((void*)decode_kernel_f32, dim3(NWG), dim3(NTHR),
                                              args, SMEM_BYTES_F32, stream);
    if (e != hipSuccess) {
      decode_kernel_f32<<<dim3(NWG), dim3(NTHR), SMEM_BYTES_F32, stream>>>(
          enc, emb, Wih, Whh, bl, Wpred, bp, Wjoin, bj, phon, out, wsf);
    }
  }
}

// Round 5
// 2704.856 us; speedup vs baseline: 8.7927x; 1.0535x over previous
//
#include <hip/hip_runtime.h>
#include <math.h>

#define TT     4000
#define DENC   1024
#define HD     1024
#define DEMB   512
#define VD     8193
#define NPH    800
#define BLANK  8192
#define NWG    256
#define NTHR   512
#define CHUNK_M 800
#define NSTEP  (NPH + 2)   // 802 sequential LSTM steps
#define NSTEPP 802
#define NVT    65          // v-tiles of 128
#define NP     129         // v-blocks of 64 (mfma partials per row)
#define CHUNK  256         // f32 fallback chunk

typedef __bf16 bf16x4 __attribute__((ext_vector_type(4)));
typedef __bf16 bf16x8 __attribute__((ext_vector_type(8)));
typedef float  f32x16 __attribute__((ext_vector_type(16)));

// ---- workspace layout (float offsets) ----
#define MEMSET_BYTES 20480
#define WSF_HX     1024                          // u64[2][1024] tagged h exchange
#define WSF_HHIST  5120                          // NSTEP x 1024
#define WSF_PREDS  826368                        // 801 x 1024
#define WSF_GXT    826368                        // ALIAS: gxT[4096][802] (dead after chain)
#define WSF_PMAX   1646592                       // TT*NP
#define WSF_PSUM   2162592
#define WSF_PARG   2678592
#define WSF_LSE    3194592                       // TT
#define WSF_AMAX   3198592                       // 1024 ints
#define WSF_XBF    3199616                       // 3328 x 1024 bf16
#define WSF_W16    4903552                       // 8320 x 1024 bf16
#define WSF_END    9163392
#define NEED_MFMA  ((size_t)WSF_END * 4)
// tstate lives inside flags page: int index 512 (byte 2048), memset-zeroed
#define TST_IDX    512
// f32 fallback layout (round-3/4, proven)
#define F_PMAX 1646592
#define F_PSUM 1906592
#define F_PARG 2166592
#define F_LSE  2426592

// ---- LDS sizes ----
#define GEMM_SMEM  12800                         // f32 tile: Wt[16][132]+Xt[16][68]
#define CHAIN_SMEM ((16 * NSTEPP + 2048 + 64) * 4)   // gxl + h dbuf + GS
#define JOIN_SMEM  (65536 + 128)
// f32 fallback LDS layout (floats)
#define S_XH   0
#define S_GS   3072
#define S_C4   3088
#define S_TOK  3264
#define S_RED  4066
#define S_AMAX 4082
#define SMEM_FLOATS_F32 4352
#define SMEM_BYTES_F32 (SMEM_FLOATS_F32 * 4)

// ======================= shared helpers =======================

__device__ __forceinline__ float dot4(float4 a, float4 b, float acc) {
  acc = fmaf(a.x, b.x, acc); acc = fmaf(a.y, b.y, acc);
  acc = fmaf(a.z, b.z, acc); acc = fmaf(a.w, b.w, acc);
  return acc;
}
__device__ __forceinline__ float sigmf(float x) { return 1.f / (1.f + expf(-x)); }
__device__ __forceinline__ float sigm_fast(float x) { return 1.f / (1.f + __expf(-x)); }
__device__ __forceinline__ float tanh_fast(float x) {
  float e = __expf(2.f * x);
  return 1.f - 2.f / (e + 1.f);
}

__device__ __forceinline__ void combine3(float& m, float& s, int& am,
                                         float om, float os, int oa) {
  float mm = fmaxf(m, om);
  s = s * __expf(m - mm) + os * __expf(om - mm);
  if (om > m || (om == m && oa < am)) am = oa;
  m = mm;
}

__device__ __forceinline__ void gload16(const void* g, void* l) {
  __builtin_amdgcn_global_load_lds(
      (const __attribute__((address_space(1))) unsigned int*)g,
      (__attribute__((address_space(3))) unsigned int*)l, 16, 0, 0);
}

__device__ __forceinline__ float ld_coh(const float* p) {
  return __hip_atomic_load((const float*)p, __ATOMIC_RELAXED, __HIP_MEMORY_SCOPE_AGENT);
}

// light barrier: flag-array + release word (data must travel via sc1 atomics)
__device__ __forceinline__ void light_barrier(unsigned* flags, unsigned& ep) {
  unsigned* arrive  = flags;
  unsigned* release = flags + 256;
  __builtin_amdgcn_s_waitcnt(0);
  __syncthreads();
  if (blockIdx.x == 0) {
    int tid = threadIdx.x;
    if (tid > 0 && tid < NWG) {
      while (__hip_atomic_load(&arrive[tid], __ATOMIC_RELAXED, __HIP_MEMORY_SCOPE_AGENT) != ep) {}
    }
    __syncthreads();
    if (tid == 0)
      __hip_atomic_store(release, ep, __ATOMIC_RELAXED, __HIP_MEMORY_SCOPE_AGENT);
  } else {
    if (threadIdx.x == 0) {
      __hip_atomic_store(&arrive[blockIdx.x], ep, __ATOMIC_RELAXED, __HIP_MEMORY_SCOPE_AGENT);
      while (__hip_atomic_load(release, __ATOMIC_RELAXED, __HIP_MEMORY_SCOPE_AGENT) != ep) {}
    }
    __syncthreads();
  }
  asm volatile("" ::: "memory");
  ep++;
}

// heavy barrier: full fence (wbl2+inv) for plain-store handoffs
__device__ __forceinline__ void heavy_barrier(unsigned* flags) {
  unsigned* bar = flags + 257;
  __syncthreads();
  if (threadIdx.x == 0) {
    __threadfence();
    unsigned g = __hip_atomic_load(&bar[1], __ATOMIC_RELAXED, __HIP_MEMORY_SCOPE_AGENT);
    unsigned v = __hip_atomic_fetch_add(&bar[0], 1u, __ATOMIC_RELAXED, __HIP_MEMORY_SCOPE_AGENT);
    if (v == (unsigned)(NWG - 1)) {
      __hip_atomic_store(&bar[0], 0u, __ATOMIC_RELAXED, __HIP_MEMORY_SCOPE_AGENT);
      __hip_atomic_store(&bar[1], g + 1u, __ATOMIC_RELEASE, __HIP_MEMORY_SCOPE_AGENT);
    } else {
      while (__hip_atomic_load(&bar[1], __ATOMIC_RELAXED, __HIP_MEMORY_SCOPE_AGENT) == g)
        __builtin_amdgcn_s_sleep(1);
    }
    __threadfence();
  }
  __syncthreads();
}

// Xbf rows: dst[j] = bf16(relu(enc[t0+j] + preds[pi])), j in [0,K)
__device__ void xbf_fill(const float* enc, const float* preds, __bf16* dst,
                         int t0, int K, int pi0, int g0, int gs) {
  int total = K << 8;
  for (int q = g0; q < total; q += gs) {
    int j = q >> 8, seg = q & 255;
    int pi = (pi0 < 0) ? NPH : pi0 + j;
    float4 e = ((const float4*)(enc + (size_t)(t0 + j) * 1024))[seg];
    float4 p = ((const float4*)(preds + (size_t)pi * 1024))[seg];
    bf16x4 r;
    r[0] = (__bf16)fmaxf(e.x + p.x, 0.f);
    r[1] = (__bf16)fmaxf(e.y + p.y, 0.f);
    r[2] = (__bf16)fmaxf(e.z + p.z, 0.f);
    r[3] = (__bf16)fmaxf(e.w + p.w, 0.f);
    *(bf16x4*)(dst + (size_t)j * 1024 + (seg << 2)) = r;
  }
}

// MFMA joiner: 128v x 128j tiles, 8 waves, mfma_f32_32x32x16_bf16, fused partials
__device__ void joiner_tiles(const __bf16* W16, const __bf16* xrows, const float* bj,
                             float* out_align, float* pmax, float* psum, int* parg,
                             char* smc, int t0, int K, int tile0, int tstride) {
  const int tid = threadIdx.x;
  const int wid = tid >> 6, lane = tid & 63;
  const int wj = wid & 3, wv = wid >> 2;
  const int l31 = lane & 31, lhi = lane >> 5;
  const int jt_n = (K + 127) >> 7;
  const int ntiles = jt_n * NVT;

  for (int tile = tile0; tile < ntiles; tile += tstride) {
    const int vt = tile % NVT, jt = tile / NVT;
    const int v0 = vt << 7, j0 = jt << 7;
    f32x16 acc0, acc1;
    #pragma unroll
    for (int i = 0; i < 16; ++i) { acc0[i] = 0.f; acc1[i] = 0.f; }

    auto stage = [&](int db, int kb) {
      char* wb = smc + db * 32768;
      char* xb = wb + 16384;
      #pragma unroll
      for (int p = 0; p < 2; ++p) {
        int sbase = p * 512 + wid * 64;
        int s = sbase + lane;
        int ks = s >> 7, r = s & 127;
        gload16(W16 + (size_t)(v0 + r) * 1024 + kb + ks * 8, wb + sbase * 16);
        gload16(xrows + (size_t)(j0 + r) * 1024 + kb + ks * 8, xb + sbase * 16);
      }
    };

    stage(0, 0);
    __syncthreads();
    int db = 0;
    for (int kb16 = 0; kb16 < 16; ++kb16) {
      if (kb16 < 15) stage(db ^ 1, (kb16 + 1) << 6);
      const char* wb = smc + db * 32768;
      const char* xb = wb + 16384;
      #pragma unroll
      for (int k16 = 0; k16 < 4; ++k16) {
        int ks = k16 * 2 + lhi;
        bf16x8 a  = *(const bf16x8*)(xb + ((ks << 7) + (wj << 5) + l31) * 16);
        bf16x8 b0 = *(const bf16x8*)(wb + ((ks << 7) + (wv << 6) + l31) * 16);
        bf16x8 b1 = *(const bf16x8*)(wb + ((ks << 7) + (wv << 6) + 32 + l31) * 16);
        acc0 = __builtin_amdgcn_mfma_f32_32x32x16_bf16(a, b0, acc0, 0, 0, 0);
        acc1 = __builtin_amdgcn_mfma_f32_32x32x16_bf16(a, b1, acc1, 0, 0, 0);
      }
      __syncthreads();
      db ^= 1;
    }

    const int v_0 = v0 + (wv << 6) + l31;
    const int v_1 = v_0 + 32;
    const float bj0 = (v_0 < VD) ? bj[v_0] : 0.f;
    const float bj1 = (v_1 < VD) ? bj[v_1] : 0.f;
    const int jbase = j0 + (wj << 5) + 4 * lhi;
    const bool npok = (v0 + (wv << 6)) < VD;
    const int np = (v0 >> 6) + wv;
    #pragma unroll
    for (int reg = 0; reg < 16; ++reg) {
      int j = jbase + (reg & 3) + 8 * (reg >> 2);
      bool jok = j < K;
      float lg0 = acc0[reg] + bj0;
      float lg1 = acc1[reg] + bj1;
      if (jok) {
        size_t ro = (size_t)(t0 + j) * VD;
        if (v_0 < VD) out_align[ro + v_0] = lg0;
        if (v_1 < VD) out_align[ro + v_1] = lg1;
      }
      float l0 = (v_0 < VD) ? lg0 : -1e30f;
      float l1 = (v_1 < VD) ? lg1 : -1e30f;
      float m = fmaxf(l0, l1);
      float ss = 0.f;
      if (v_0 < VD) ss += __expf(l0 - m);
      if (v_1 < VD) ss += __expf(l1 - m);
      int am = (l1 > l0) ? v_1 : v_0;
      #pragma unroll
      for (int msk = 1; msk <= 16; msk <<= 1) {
        float om = __shfl_xor(m, msk, 64);
        float os = __shfl_xor(ss, msk, 64);
        int oa = __shfl_xor(am, msk, 64);
        float mm = fmaxf(m, om);
        ss = ss * __expf(m - mm) + os * __expf(om - mm);
        if (om > m || (om == m && oa < am)) am = oa;
        m = mm;
      }
      if (l31 == 0 && jok && npok) {
        size_t pb = (size_t)(t0 + j) * NP + np;
        __hip_atomic_store(&pmax[pb], m, __ATOMIC_RELAXED, __HIP_MEMORY_SCOPE_AGENT);
        __hip_atomic_store(&psum[pb], ss, __ATOMIC_RELAXED, __HIP_MEMORY_SCOPE_AGENT);
        __hip_atomic_store(&parg[pb], am, __ATOMIC_RELAXED, __HIP_MEMORY_SCOPE_AGENT);
      }
    }
  }
}

__device__ __forceinline__ void merge_row129(const float* pmax, const float* psum,
                                             const int* parg, int row, int lane,
                                             float& m, float& s, int& am) {
  size_t b = (size_t)row * NP;
  m = ld_coh(pmax + b + lane);
  s = ld_coh(psum + b + lane);
  am = __hip_atomic_load(&parg[b + lane], __ATOMIC_RELAXED, __HIP_MEMORY_SCOPE_AGENT);
  {
    int i2 = lane + 64;
    float om = ld_coh(pmax + b + i2);
    float os = ld_coh(psum + b + i2);
    int oa = __hip_atomic_load(&parg[b + i2], __ATOMIC_RELAXED, __HIP_MEMORY_SCOPE_AGENT);
    combine3(m, s, am, om, os, oa);
  }
  if (lane == 0) {
    float om = ld_coh(pmax + b + 128);
    float os = ld_coh(psum + b + 128);
    int oa = __hip_atomic_load(&parg[b + 128], __ATOMIC_RELAXED, __HIP_MEMORY_SCOPE_AGENT);
    combine3(m, s, am, om, os, oa);
  }
  #pragma unroll
  for (int msk = 32; msk; msk >>= 1) {
    float om = __shfl_xor(m, msk, 64);
    float os = __shfl_xor(s, msk, 64);
    int oa = __shfl_xor(am, msk, 64);
    combine3(m, s, am, om, os, oa);
  }
}

// ======================= K1a: W_join -> bf16 =======================
__global__ __launch_bounds__(512) void wconv_kernel(const float* __restrict__ Wjoin,
                                                    float* wsf) {
  __bf16* w16 = (__bf16*)(wsf + WSF_W16);
  int g0 = blockIdx.x * 512 + threadIdx.x;
  int gs = gridDim.x * 512;
  for (int q = g0; q < VD * 256; q += gs) {
    int v = q >> 8, seg = q & 255;
    float4 w4 = ((const float4*)(Wjoin + (size_t)v * 1024))[seg];
    bf16x4 r;
    r[0] = (__bf16)w4.x; r[1] = (__bf16)w4.y; r[2] = (__bf16)w4.z; r[3] = (__bf16)w4.w;
    *(bf16x4*)(w16 + (size_t)v * 1024 + (seg << 2)) = r;
  }
}

// ======================= K1b: gxT[gr][s] = Wih@emb[tok_s] + bl ==============
__global__ __launch_bounds__(512) void gx_kernel(
    const float* __restrict__ Wih, const float* __restrict__ emb,
    const float* __restrict__ bl, const int* __restrict__ phon, float* wsf) {
  extern __shared__ float sm[];
  float* Wt = sm;          // [16][132]
  float* Xt = sm + 2112;   // [16][68]
  float* gxT = wsf + WSF_GXT;
  const int tid = threadIdx.x;
  const int tx = tid & 31, ty = tid >> 5;
  int ntiles = 32 * 13;
  for (int tile = blockIdx.x; tile < ntiles; tile += gridDim.x) {
    int vt = tile & 31, jt = tile >> 5;
    int v0 = vt * 128, j0 = jt * 64;
    float acc[4][4];
    #pragma unroll
    for (int a = 0; a < 4; ++a)
      #pragma unroll
      for (int q = 0; q < 4; ++q) acc[a][q] = 0.f;
    for (int kk = 0; kk < DEMB; kk += 16) {
      {
        int r = tid >> 2, seg = tid & 3;
        float4 wv = ((const float4*)(Wih + (size_t)(v0 + r) * DEMB + kk))[seg];
        Wt[(seg * 4 + 0) * 132 + r] = wv.x;
        Wt[(seg * 4 + 1) * 132 + r] = wv.y;
        Wt[(seg * 4 + 2) * 132 + r] = wv.z;
        Wt[(seg * 4 + 3) * 132 + r] = wv.w;
      }
      if (tid < 256) {
        int r = tid >> 2, seg = tid & 3;
        int j = j0 + r;
        float4 xv = make_float4(0.f, 0.f, 0.f, 0.f);
        if (j < NSTEP) {
          int tok = (j < 2) ? BLANK : phon[j - 2];
          xv = ((const float4*)(emb + (size_t)tok * DEMB + kk))[seg];
        }
        Xt[(seg * 4 + 0) * 68 + r] = xv.x;
        Xt[(seg * 4 + 1) * 68 + r] = xv.y;
        Xt[(seg * 4 + 2) * 68 + r] = xv.z;
        Xt[(seg * 4 + 3) * 68 + r] = xv.w;
      }
      __syncthreads();
      #pragma unroll
      for (int k = 0; k < 16; ++k) {
        float4 a = *(const float4*)(Wt + k * 132 + (tx << 2));
        float4 bq = *(const float4*)(Xt + k * 68 + (ty << 2));
        acc[0][0] = fmaf(a.x, bq.x, acc[0][0]); acc[1][0] = fmaf(a.y, bq.x, acc[1][0]);
        acc[2][0] = fmaf(a.z, bq.x, acc[2][0]); acc[3][0] = fmaf(a.w, bq.x, acc[3][0]);
        acc[0][1] = fmaf(a.x, bq.y, acc[0][1]); acc[1][1] = fmaf(a.y, bq.y, acc[1][1]);
        acc[2][1] = fmaf(a.z, bq.y, acc[2][1]); acc[3][1] = fmaf(a.w, bq.y, acc[3][1]);
        acc[0][2] = fmaf(a.x, bq.z, acc[0][2]); acc[1][2] = fmaf(a.y, bq.z, acc[1][2]);
        acc[2][2] = fmaf(a.z, bq.z, acc[2][2]); acc[3][2] = fmaf(a.w, bq.z, acc[3][2]);
        acc[0][3] = fmaf(a.x, bq.w, acc[0][3]); acc[1][3] = fmaf(a.y, bq.w, acc[1][3]);
        acc[2][3] = fmaf(a.z, bq.w, acc[2][3]); acc[3][3] = fmaf(a.w, bq.w, acc[3][3]);
      }
      __syncthreads();
    }
    int vb = v0 + (tx << 2), jb0 = j0 + (ty << 2);
    #pragma unroll
    for (int jj = 0; jj < 4; ++jj) {
      int j = jb0 + jj;
      if (j >= NSTEP) continue;
      #pragma unroll
      for (int q = 0; q < 4; ++q)
        gxT[(size_t)(vb + q) * NSTEPP + j] = acc[q][jj] + bl[vb + q];
    }
  }
}

// ======================= K2: sequential LSTM chain (coop, 256 WGs) ==========
__global__ __launch_bounds__(NTHR) void chain_kernel(const float* __restrict__ Whh,
                                                     float* wsf) {
  extern __shared__ float sm[];
  float* gxl = sm;                  // [16][802]
  float* hb  = sm + 16 * NSTEPP;    // [2][1024]
  float* GS  = hb + 2048;           // [16]
  const int tid = threadIdx.x;
  const int w = tid >> 6, l = tid & 63;
  const int b = blockIdx.x;
  const float* gxT = wsf + WSF_GXT;
  float* hhist = wsf + WSF_HHIST;
  unsigned long long* hx = (unsigned long long*)(wsf + WSF_HX);

  // register-resident Whh slices: wave w rows rr0=2w, rr1=2w+1 (rr = q*4+j)
  float4 W0[4], W1[4];
  {
    int rr0 = 2 * w, rr1 = 2 * w + 1;
    int gr0 = ((rr0 >> 2) << 10) + 4 * b + (rr0 & 3);
    int gr1 = ((rr1 >> 2) << 10) + 4 * b + (rr1 & 3);
    const float4* h0 = (const float4*)(Whh + (size_t)gr0 * HD);
    const float4* h1 = (const float4*)(Whh + (size_t)gr1 * HD);
    #pragma unroll
    for (int i = 0; i < 4; ++i) { W0[i] = h0[l + 64 * i]; W1[i] = h1[l + 64 * i]; }
  }
  // LDS-preload the gx slice for this WG's 16 rows (all 802 steps)
  for (int rr = 0; rr < 16; ++rr) {
    int gr = ((rr >> 2) << 10) + 4 * b + (rr & 3);
    for (int s = tid; s < NSTEP; s += NTHR)
      gxl[rr * NSTEPP + s] = gxT[(size_t)gr * NSTEPP + s];
  }
  for (int i = tid; i < 1024; i += NTHR) hb[i] = 0.f;   // h(0) = 0 in buffer 0
  __syncthreads();

  float c_reg = 0.f;
  for (int s = 0; s < NSTEP; ++s) {
    int p = s & 1;
    const float4* h4 = (const float4*)(hb + p * 1024);
    float a0 = 0.f, a1 = 0.f;
    #pragma unroll
    for (int i = 0; i < 4; ++i) {
      float4 hv = h4[l + 64 * i];
      a0 = dot4(W0[i], hv, a0);
      a1 = dot4(W1[i], hv, a1);
    }
    #pragma unroll
    for (int m = 32; m; m >>= 1) {
      a0 += __shfl_xor(a0, m, 64);
      a1 += __shfl_xor(a1, m, 64);
    }
    if (l == 0) { GS[2 * w] = a0; GS[2 * w + 1] = a1; }
    __syncthreads();
    if (tid < 4) {
      int j = tid;
      float gi = GS[j]      + gxl[j * NSTEPP + s];
      float gf = GS[4 + j]  + gxl[(4 + j) * NSTEPP + s];
      float gg = GS[8 + j]  + gxl[(8 + j) * NSTEPP + s];
      float go = GS[12 + j] + gxl[(12 + j) * NSTEPP + s];
      float c2 = sigm_fast(gf) * c_reg + sigm_fast(gi) * tanh_fast(gg);
      float h2 = sigm_fast(go) * tanh_fast(c2);
      c_reg = c2;
      int cell = 4 * b + j;
      hhist[(size_t)s * HD + cell] = h2;
      unsigned long long pk = ((unsigned long long)(unsigned)(s + 1) << 32)
                            | (unsigned long long)__float_as_uint(h2);
      __hip_atomic_store(&hx[(p ^ 1) * 1024 + cell], pk,
                         __ATOMIC_RELAXED, __HIP_MEMORY_SCOPE_AGENT);
    }
    if (s + 1 < NSTEP) {
      unsigned tg = (unsigned)(s + 1);
      const unsigned long long* src = hx + (p ^ 1) * 1024;
      unsigned long long v0, v1;
      do {  // single combined poll: both loads in flight per retry
        v0 = __hip_atomic_load(&src[2 * tid],     __ATOMIC_RELAXED, __HIP_MEMORY_SCOPE_AGENT);
        v1 = __hip_atomic_load(&src[2 * tid + 1], __ATOMIC_RELAXED, __HIP_MEMORY_SCOPE_AGENT);
      } while ((unsigned)(v0 >> 32) != tg || (unsigned)(v1 >> 32) != tg);
      float* dst = hb + (p ^ 1) * 1024 + 2 * tid;
      dst[0] = __uint_as_float((unsigned)v0);
      dst[1] = __uint_as_float((unsigned)v1);
    }
    __syncthreads();
  }
}

// ======================= K2b: preds = W_pred @ hhist + bp ===================
__global__ __launch_bounds__(512) void preds_kernel(
    const float* __restrict__ Wpred, const float* __restrict__ bp, float* wsf) {
  extern __shared__ float sm[];
  float* Wt = sm;
  float* Xt = sm + 2112;
  const float* hhist = wsf + WSF_HHIST;
  float* preds = wsf + WSF_PREDS;
  const int tid = threadIdx.x;
  const int tx = tid & 31, ty = tid >> 5;
  int ntiles = 8 * 13;
  for (int tile = blockIdx.x; tile < ntiles; tile += gridDim.x) {
    int vt = tile & 7, jt = tile >> 3;
    int v0 = vt * 128, j0 = jt * 64;
    float acc[4][4];
    #pragma unroll
    for (int a = 0; a < 4; ++a)
      #pragma unroll
      for (int q = 0; q < 4; ++q) acc[a][q] = 0.f;
    for (int kk = 0; kk < 1024; kk += 16) {
      {
        int r = tid >> 2, seg = tid & 3;
        float4 wv = ((const float4*)(Wpred + (size_t)(v0 + r) * HD + kk))[seg];
        Wt[(seg * 4 + 0) * 132 + r] = wv.x;
        Wt[(seg * 4 + 1) * 132 + r] = wv.y;
        Wt[(seg * 4 + 2) * 132 + r] = wv.z;
        Wt[(seg * 4 + 3) * 132 + r] = wv.w;
      }
      if (tid < 256) {
        int r = tid >> 2, seg = tid & 3;
        int j = j0 + r;
        float4 xv = make_float4(0.f, 0.f, 0.f, 0.f);
        if (j <= NPH) xv = ((const float4*)(hhist + (size_t)(j + 1) * HD + kk))[seg];
        Xt[(seg * 4 + 0) * 68 + r] = xv.x;
        Xt[(seg * 4 + 1) * 68 + r] = xv.y;
        Xt[(seg * 4 + 2) * 68 + r] = xv.z;
        Xt[(seg * 4 + 3) * 68 + r] = xv.w;
      }
      __syncthreads();
      #pragma unroll
      for (int k = 0; k < 16; ++k) {
        float4 a = *(const float4*)(Wt + k * 132 + (tx << 2));
        float4 bq = *(const float4*)(Xt + k * 68 + (ty << 2));
        acc[0][0] = fmaf(a.x, bq.x, acc[0][0]); acc[1][0] = fmaf(a.y, bq.x, acc[1][0]);
        acc[2][0] = fmaf(a.z, bq.x, acc[2][0]); acc[3][0] = fmaf(a.w, bq.x, acc[3][0]);
        acc[0][1] = fmaf(a.x, bq.y, acc[0][1]); acc[1][1] = fmaf(a.y, bq.y, acc[1][1]);
        acc[2][1] = fmaf(a.z, bq.y, acc[2][1]); acc[3][1] = fmaf(a.w, bq.y, acc[3][1]);
        acc[0][2] = fmaf(a.x, bq.z, acc[0][2]); acc[1][2] = fmaf(a.y, bq.z, acc[1][2]);
        acc[2][2] = fmaf(a.z, bq.z, acc[2][2]); acc[3][2] = fmaf(a.w, bq.z, acc[3][2]);
        acc[0][3] = fmaf(a.x, bq.w, acc[0][3]); acc[1][3] = fmaf(a.y, bq.w, acc[1][3]);
        acc[2][3] = fmaf(a.z, bq.w, acc[2][3]); acc[3][3] = fmaf(a.w, bq.w, acc[3][3]);
      }
      __syncthreads();
    }
    int vb = v0 + (tx << 2), jb0 = j0 + (ty << 2);
    #pragma unroll
    for (int jj = 0; jj < 4; ++jj) {
      int j = jb0 + jj;
      if (j > NPH) continue;
      #pragma unroll
      for (int q = 0; q < 4; ++q)
        preds[(size_t)j * 1024 + vb + q] = acc[q][jj] + bp[vb + q];
    }
  }
}

// ======================= K2c: speculative-chunk xbf =========================
__global__ void xspec_kernel(const float* __restrict__ enc, float* wsf) {
  xbf_fill(enc, wsf + WSF_PREDS, (__bf16*)(wsf + WSF_XBF), 0, CHUNK_M, 0,
           blockIdx.x * blockDim.x + threadIdx.x, gridDim.x * blockDim.x);
}

// ======================= K3a: speculative joiner (plain, 2 WG/CU) ===========
__global__ __launch_bounds__(NTHR) void joinspec_kernel(const float* __restrict__ bj,
                                                        float* out, float* wsf) {
  extern __shared__ float sm[];
  joiner_tiles((__bf16*)(wsf + WSF_W16), (__bf16*)(wsf + WSF_XBF), bj, out,
               wsf + WSF_PMAX, wsf + WSF_PSUM, (int*)(wsf + WSF_PARG),
               (char*)sm, 0, CHUNK_M, blockIdx.x, gridDim.x);
}

// ======================= K3b: decode loop (coop) ============================
__global__ __launch_bounds__(NTHR) void decode_coop(
    const float* enc, const float* bj, const int* phon, float* out, float* wsf) {
  extern __shared__ float sm[];
  char* smc = (char*)sm;
  unsigned* flags = (unsigned*)wsf;
  float* preds = wsf + WSF_PREDS;
  float* pmax = wsf + WSF_PMAX;
  float* psum = wsf + WSF_PSUM;
  int* parg = (int*)(wsf + WSF_PARG);
  float* lse = wsf + WSF_LSE;
  int* amaxws = (int*)(wsf + WSF_AMAX);
  __bf16* xbf = (__bf16*)(wsf + WSF_XBF);
  __bf16* w16 = (__bf16*)(wsf + WSF_W16);
  float* out_pred  = out + (size_t)TT * VD;
  float* out_valid = out + (size_t)TT * VD + TT;

  const int tid = threadIdx.x;
  const int wid = tid >> 6, lane = tid & 63;
  unsigned ep = 1;
  int t = 0, tp = 0, iter = 0;

  while (t < TT && tp < NPH) {
    int K = CHUNK_M;
    if (TT - t < K) K = TT - t;
    if (NPH - tp < K) K = NPH - tp;
    if (iter > 0) {   // rare rollback path: recompute chunk with corrected preds
      heavy_barrier(flags);
      xbf_fill(enc, preds, xbf, t, K, tp, blockIdx.x * NTHR + tid, gridDim.x * NTHR);
      heavy_barrier(flags);
      joiner_tiles(w16, xbf, bj, out, pmax, psum, parg, smc, t, K,
                   blockIdx.x, gridDim.x);
    }
    light_barrier(flags, ep);
    for (int j = blockIdx.x * 8 + wid; j < K; j += gridDim.x * 8) {
      float m, s; int am;
      merge_row129(pmax, psum, parg, t + j, lane, m, s, am);
      if (lane == 0) {
        __hip_atomic_store(&amaxws[j], am, __ATOMIC_RELAXED, __HIP_MEMORY_SCOPE_AGENT);
        lse[t + j] = m + logf(s);
      }
    }
    light_barrier(flags, ep);
    // decision: first blank (redundant per WG -> uniform)
    int cand = K;
    for (int idx = tid; idx < K; idx += NTHR) {
      int a = __hip_atomic_load(&amaxws[idx], __ATOMIC_RELAXED, __HIP_MEMORY_SCOPE_AGENT);
      if (a == BLANK && idx < cand) cand = idx;
    }
    #pragma unroll
    for (int msk = 32; msk; msk >>= 1) cand = min(cand, __shfl_xor(cand, msk, 64));
    int* red = (int*)(smc + 65536);
    if (lane == 0) red[wid] = cand;
    __syncthreads();
    if (tid == 0) {
      int mn = red[0];
      for (int w2 = 1; w2 < 8; ++w2) mn = min(mn, red[w2]);
      red[8] = mn;
    }
    __syncthreads();
    int jb = red[8];
    __syncthreads();
    int nacc = (jb < K) ? jb + 1 : K;
    int nadv = (jb < K) ? jb : K;
    if (blockIdx.x == 0) {
      for (int j = tid; j < nacc; j += NTHR) {
        out_pred[t + j] = (j == jb) ? (float)BLANK : (float)phon[tp + j];
        out_valid[t + j] = 1.f;
      }
    }
    t += nacc; tp += nadv; ++iter;
  }

  // tail xbf: rows [t,TT) all use preds[NPH]; consumed by jointail after boundary
  if (t < TT) {
    xbf_fill(enc, preds, xbf + (size_t)(t - 800) * 1024, t, TT - t, -1,
             blockIdx.x * NTHR + tid, gridDim.x * NTHR);
  }
  if (blockIdx.x == 0 && tid == 0) ((int*)wsf)[TST_IDX] = t;
}

// ======================= K4: tail joiner (plain, 2 WG/CU) ===================
__global__ __launch_bounds__(NTHR) void jointail_kernel(const float* __restrict__ bj,
                                                        float* out, float* wsf) {
  extern __shared__ float sm[];
  int t = ((const int*)wsf)[TST_IDX];
  if (t >= TT) return;
  joiner_tiles((__bf16*)(wsf + WSF_W16),
               (__bf16*)(wsf + WSF_XBF) + (size_t)(t - 800) * 1024, bj, out,
               wsf + WSF_PMAX, wsf + WSF_PSUM, (int*)(wsf + WSF_PARG),
               (char*)sm, t, TT - t, blockIdx.x, gridDim.x);
}

// ======================= K5: tail merge -> lse, pred/valid ==================
__global__ __launch_bounds__(NTHR) void mergetail_kernel(float* out, float* wsf) {
  int t = ((const int*)wsf)[TST_IDX];
  float* lse = wsf + WSF_LSE;
  float* out_pred  = out + (size_t)TT * VD;
  float* out_valid = out + (size_t)TT * VD + TT;
  const int wid = threadIdx.x >> 6, lane = threadIdx.x & 63;
  for (int row = t + blockIdx.x * 8 + wid; row < TT; row += gridDim.x * 8) {
    float m, s; int am;
    merge_row129(wsf + WSF_PMAX, wsf + WSF_PSUM, (const int*)(wsf + WSF_PARG),
                 row, lane, m, s, am);
    if (lane == 0) {
      lse[row] = m + logf(s);
      out_pred[row] = (float)BLANK;
      out_valid[row] = 0.f;
    }
  }
}

// ======================= K6: logp = logits - lse ============================
__global__ __launch_bounds__(256) void sub_kernel(float* out, const float* wsf) {
  const float* lse = wsf + WSF_LSE;
  for (int row = blockIdx.x; row < TT; row += gridDim.x) {
    float l = lse[row];
    float* p = out + (size_t)row * VD;
    for (int i = threadIdx.x; i < VD; i += 256) p[i] -= l;
  }
}

// ======================= f32 fallback (round-3/4, proven) ===================
struct Ctx {
  const float *enc, *emb, *Wih, *Whh, *bl, *Wpred, *bp, *Wjoin, *bj;
  const int* phon;
  unsigned long long* hx;
  float *hhist, *preds, *pmax, *psum, *lse;
  int* parg;
  unsigned* flags;
  float *out_align, *out_pred, *out_valid;
};

__device__ void chain_all_legacy(const Ctx& C, float* sm) {
  const int tid = threadIdx.x;
  const int w = tid >> 6, l = tid & 63;
  const int b = blockIdx.x;
  int* tok_sm = (int*)(sm + S_TOK);
  for (int s = tid; s < NSTEP; s += NTHR)
    tok_sm[s] = (s < 2) ? BLANK : C.phon[s - 2];
  float4 W0[6], W1[6];
  {
    int rr0 = 2 * w, rr1 = 2 * w + 1;
    int gr0 = ((rr0 >> 2) << 10) + 4 * b + (rr0 & 3);
    int gr1 = ((rr1 >> 2) << 10) + 4 * b + (rr1 & 3);
    const float4* ih0 = (const float4*)(C.Wih + (size_t)gr0 * DEMB);
    const float4* hh0 = (const float4*)(C.Whh + (size_t)gr0 * HD);
    const float4* ih1 = (const float4*)(C.Wih + (size_t)gr1 * DEMB);
    const float4* hh1 = (const float4*)(C.Whh + (size_t)gr1 * HD);
    W0[0] = ih0[l];       W0[1] = ih0[64 + l];
    W0[2] = hh0[l];       W0[3] = hh0[64 + l];
    W0[4] = hh0[128 + l]; W0[5] = hh0[192 + l];
    W1[0] = ih1[l];       W1[1] = ih1[64 + l];
    W1[2] = hh1[l];       W1[3] = hh1[64 + l];
    W1[4] = hh1[128 + l]; W1[5] = hh1[192 + l];
  }
  float bi = 0.f, bf = 0.f, bg = 0.f, bo = 0.f;
  if (tid < 4) {
    bi = C.bl[4 * b + tid];
    bf = C.bl[1024 + 4 * b + tid];
    bg = C.bl[2048 + 4 * b + tid];
    bo = C.bl[3072 + 4 * b + tid];
    sm[S_C4 + tid] = 0.f;
  }
  for (int i = tid; i < 1536; i += NTHR) sm[S_XH + i] = 0.f;
  if (tid < 512) sm[S_XH + tid] = C.emb[(size_t)BLANK * DEMB + tid];
  __syncthreads();
  unsigned long long* hx = C.hx;
  for (int s = 0; s < NSTEP; ++s) {
    int p = s & 1;
    const float4* xh4 = (const float4*)(sm + S_XH + p * 1536);
    float a0 = 0.f, a1 = 0.f;
    #pragma unroll
    for (int i = 0; i < 6; ++i) {
      float4 v = xh4[i * 64 + l];
      a0 = dot4(W0[i], v, a0);
      a1 = dot4(W1[i], v, a1);
    }
    #pragma unroll
    for (int m = 32; m; m >>= 1) {
      a0 += __shfl_xor(a0, m, 64);
      a1 += __shfl_xor(a1, m, 64);
    }
    if (l == 0) { sm[S_GS + 2 * w] = a0; sm[S_GS + 2 * w + 1] = a1; }
    if (s + 1 < NSTEP && tid < 512)
      sm[S_XH + (1 - p) * 1536 + tid] = C.emb[(size_t)tok_sm[s + 1] * DEMB + tid];
    __syncthreads();
    if (tid < 4) {
      int j = tid;
      float gi = sm[S_GS + j]      + bi;
      float gf = sm[S_GS + 4 + j]  + bf;
      float gg = sm[S_GS + 8 + j]  + bg;
      float go = sm[S_GS + 12 + j] + bo;
      float cc = sm[S_C4 + j];
      float c2 = sigmf(gf) * cc + sigmf(gi) * tanhf(gg);
      float h2 = sigmf(go) * tanhf(c2);
      sm[S_C4 + j] = c2;
      int cell = 4 * b + j;
      C.hhist[(size_t)s * HD + cell] = h2;
      unsigned long long pk = ((unsigned long long)(unsigned)(s + 1) << 32)
                            | (unsigned long long)__float_as_uint(h2);
      __hip_atomic_store(&hx[(1 - p) * 1024 + cell], pk,
                         __ATOMIC_RELAXED, __HIP_MEMORY_SCOPE_AGENT);
    }
    if (s + 1 < NSTEP) {
      unsigned tg = (unsigned)(s + 1);
      #pragma unroll
      for (int kq = 0; kq < 2; ++kq) {
        int k = tid + kq * 512;
        unsigned long long v;
        do {
          v = __hip_atomic_load(&hx[(1 - p) * 1024 + k],
                                __ATOMIC_RELAXED, __HIP_MEMORY_SCOPE_AGENT);
        } while ((unsigned)(v >> 32) != tg);
        sm[S_XH + (1 - p) * 1536 + 512 + k] = __uint_as_float((unsigned)v);
      }
    }
    __syncthreads();
  }
}

__device__ void preds_gemm_legacy(const Ctx& C, float* sm) {
  float* Wt = sm;
  float* Xt = sm + 2112;
  const int tid = threadIdx.x;
  const int tx = tid & 31, ty = tid >> 5;
  int ntiles = 8 * 13;
  for (int tile = blockIdx.x; tile < ntiles; tile += NWG) {
    int vt = tile & 7, jt = tile >> 3;
    int v0 = vt * 128, j0 = jt * 64;
    float acc[4][4];
    #pragma unroll
    for (int a = 0; a < 4; ++a)
      #pragma unroll
      for (int q = 0; q < 4; ++q) acc[a][q] = 0.f;
    for (int kk = 0; kk < 1024; kk += 16) {
      {
        int r = tid >> 2, seg = tid & 3;
        float4 wv = ((const float4*)(C.Wpred + (size_t)(v0 + r) * HD + kk))[seg];
        Wt[(seg * 4 + 0) * 132 + r] = wv.x;
        Wt[(seg * 4 + 1) * 132 + r] = wv.y;
        Wt[(seg * 4 + 2) * 132 + r] = wv.z;
        Wt[(seg * 4 + 3) * 132 + r] = wv.w;
      }
      if (tid < 256) {
        int r = tid >> 2, seg = tid & 3;
        int j = j0 + r;
        float4 xv = make_float4(0.f, 0.f, 0.f, 0.f);
        if (j <= NPH) xv = ((const float4*)(C.hhist + (size_t)(j + 1) * HD + kk))[seg];
        Xt[(seg * 4 + 0) * 68 + r] = xv.x;
        Xt[(seg * 4 + 1) * 68 + r] = xv.y;
        Xt[(seg * 4 + 2) * 68 + r] = xv.z;
        Xt[(seg * 4 + 3) * 68 + r] = xv.w;
      }
      __syncthreads();
      #pragma unroll
      for (int k = 0; k < 16; ++k) {
        float4 a = *(const float4*)(Wt + k * 132 + (tx << 2));
        float4 bq = *(const float4*)(Xt + k * 68 + (ty << 2));
        acc[0][0] = fmaf(a.x, bq.x, acc[0][0]); acc[1][0] = fmaf(a.y, bq.x, acc[1][0]);
        acc[2][0] = fmaf(a.z, bq.x, acc[2][0]); acc[3][0] = fmaf(a.w, bq.x, acc[3][0]);
        acc[0][1] = fmaf(a.x, bq.y, acc[0][1]); acc[1][1] = fmaf(a.y, bq.y, acc[1][1]);
        acc[2][1] = fmaf(a.z, bq.y, acc[2][1]); acc[3][1] = fmaf(a.w, bq.y, acc[3][1]);
        acc[0][2] = fmaf(a.x, bq.z, acc[0][2]); acc[1][2] = fmaf(a.y, bq.z, acc[1][2]);
        acc[2][2] = fmaf(a.z, bq.z, acc[2][2]); acc[3][2] = fmaf(a.w, bq.z, acc[3][2]);
        acc[0][3] = fmaf(a.x, bq.w, acc[0][3]); acc[1][3] = fmaf(a.y, bq.w, acc[1][3]);
        acc[2][3] = fmaf(a.z, bq.w, acc[2][3]); acc[3][3] = fmaf(a.w, bq.w, acc[3][3]);
      }
      __syncthreads();
    }
    int vb = v0 + (tx << 2), jb0 = j0 + (ty << 2);
    #pragma unroll
    for (int jj = 0; jj < 4; ++jj) {
      int j = jb0 + jj;
      if (j > NPH) continue;
      #pragma unroll
      for (int q = 0; q < 4; ++q)
        C.preds[(size_t)j * 1024 + vb + q] = acc[q][jj] + C.bp[vb + q];
    }
  }
}

__device__ void joiner_gemm_f32(const Ctx& C, float* sm, int t0, int K, int pi0) {
  float* Wt = sm;
  float* Xt = sm + 2112;
  const int tid = threadIdx.x;
  const int tx = tid & 31, ty = tid >> 5;
  int jt_n = (K + 63) >> 6;
  int ntiles = jt_n * NVT;
  for (int tile = blockIdx.x; tile < ntiles; tile += NWG) {
    int vt = tile % NVT, jt = tile / NVT;
    int v0 = vt * 128, j0 = jt * 64;
    float acc[4][4];
    #pragma unroll
    for (int a = 0; a < 4; ++a)
      #pragma unroll
      for (int q = 0; q < 4; ++q) acc[a][q] = 0.f;
    for (int kk = 0; kk < 1024; kk += 16) {
      {
        int r = tid >> 2, seg = tid & 3;
        int v = v0 + r;
        float4 wv = make_float4(0.f, 0.f, 0.f, 0.f);
        if (v < VD) wv = ((const float4*)(C.Wjoin + (size_t)v * 1024 + kk))[seg];
        Wt[(seg * 4 + 0) * 132 + r] = wv.x;
        Wt[(seg * 4 + 1) * 132 + r] = wv.y;
        Wt[(seg * 4 + 2) * 132 + r] = wv.z;
        Wt[(seg * 4 + 3) * 132 + r] = wv.w;
      }
      if (tid < 256) {
        int r = tid >> 2, seg = tid & 3;
        int j = j0 + r;
        float4 xv = make_float4(0.f, 0.f, 0.f, 0.f);
        if (j < K) {
          int pi = (pi0 < 0) ? NPH : (pi0 + j);
          float4 e = ((const float4*)(C.enc + (size_t)(t0 + j) * DENC + kk))[seg];
          float4 pr = ((const float4*)(C.preds + (size_t)pi * 1024 + kk))[seg];
          xv.x = fmaxf(e.x + pr.x, 0.f);
          xv.y = fmaxf(e.y + pr.y, 0.f);
          xv.z = fmaxf(e.z + pr.z, 0.f);
          xv.w = fmaxf(e.w + pr.w, 0.f);
        }
        Xt[(seg * 4 + 0) * 68 + r] = xv.x;
        Xt[(seg * 4 + 1) * 68 + r] = xv.y;
        Xt[(seg * 4 + 2) * 68 + r] = xv.z;
        Xt[(seg * 4 + 3) * 68 + r] = xv.w;
      }
      __syncthreads();
      #pragma unroll
      for (int k = 0; k < 16; ++k) {
        float4 a = *(const float4*)(Wt + k * 132 + (tx << 2));
        float4 bq = *(const float4*)(Xt + k * 68 + (ty << 2));
        acc[0][0] = fmaf(a.x, bq.x, acc[0][0]); acc[1][0] = fmaf(a.y, bq.x, acc[1][0]);
        acc[2][0] = fmaf(a.z, bq.x, acc[2][0]); acc[3][0] = fmaf(a.w, bq.x, acc[3][0]);
        acc[0][1] = fmaf(a.x, bq.y, acc[0][1]); acc[1][1] = fmaf(a.y, bq.y, acc[1][1]);
        acc[2][1] = fmaf(a.z, bq.y, acc[2][1]); acc[3][1] = fmaf(a.w, bq.y, acc[3][1]);
        acc[0][2] = fmaf(a.x, bq.z, acc[0][2]); acc[1][2] = fmaf(a.y, bq.z, acc[1][2]);
        acc[2][2] = fmaf(a.z, bq.z, acc[2][2]); acc[3][2] = fmaf(a.w, bq.z, acc[3][2]);
        acc[0][3] = fmaf(a.x, bq.w, acc[0][3]); acc[1][3] = fmaf(a.y, bq.w, acc[1][3]);
        acc[2][3] = fmaf(a.z, bq.w, acc[2][3]); acc[3][3] = fmaf(a.w, bq.w, acc[3][3]);
      }
      __syncthreads();
    }
    int vb = v0 + (tx << 2);
    int jb0 = j0 + (ty << 2);
    float bjv[4];
    #pragma unroll
    for (int q = 0; q < 4; ++q) bjv[q] = (vb + q < VD) ? C.bj[vb + q] : 0.f;
    #pragma unroll
    for (int jj = 0; jj < 4; ++jj) {
      int j = jb0 + jj;
      if (j >= K) continue;
      size_t ro = (size_t)(t0 + j) * VD;
      float lg[4];
      float m = -1e30f; int am = vb;
      #pragma unroll
      for (int q = 0; q < 4; ++q) {
        int v = vb + q;
        if (v < VD) {
          lg[q] = acc[q][jj] + bjv[q];
          C.out_align[ro + v] = lg[q];
          if (lg[q] > m) { m = lg[q]; am = v; }
        } else lg[q] = -1e30f;
      }
      float ss = 0.f;
      #pragma unroll
      for (int q = 0; q < 4; ++q)
        if (vb + q < VD) ss += __expf(lg[q] - m);
      #pragma unroll
      for (int msk = 16; msk; msk >>= 1) {
        float om = __shfl_xor(m, msk, 64);
        float os = __shfl_xor(ss, msk, 64);
        int oa = __shfl_xor(am, msk, 64);
        combine3(m, ss, am, om, os, oa);
      }
      if (tx == 0) {
        size_t pb = (size_t)(t0 + j) * NVT + vt;
        __hip_atomic_store(&C.pmax[pb], m, __ATOMIC_RELAXED, __HIP_MEMORY_SCOPE_AGENT);
        __hip_atomic_store(&C.psum[pb], ss, __ATOMIC_RELAXED, __HIP_MEMORY_SCOPE_AGENT);
        __hip_atomic_store(&C.parg[pb], am, __ATOMIC_RELAXED, __HIP_MEMORY_SCOPE_AGENT);
      }
    }
  }
}

__device__ __forceinline__ void merge_row65(const Ctx& C, int row, int lane,
                                            float& m, float& s, int& am) {
  size_t b = (size_t)row * NVT;
  m = ld_coh(C.pmax + b + lane);
  s = ld_coh(C.psum + b + lane);
  am = __hip_atomic_load(&C.parg[b + lane], __ATOMIC_RELAXED, __HIP_MEMORY_SCOPE_AGENT);
  if (lane == 0) {
    float om = ld_coh(C.pmax + b + 64);
    float os = ld_coh(C.psum + b + 64);
    int oa = __hip_atomic_load(&C.parg[b + 64], __ATOMIC_RELAXED, __HIP_MEMORY_SCOPE_AGENT);
    combine3(m, s, am, om, os, oa);
  }
  #pragma unroll
  for (int msk = 32; msk; msk >>= 1) {
    float om = __shfl_xor(m, msk, 64);
    float os = __shfl_xor(s, msk, 64);
    int oa = __shfl_xor(am, msk, 64);
    combine3(m, s, am, om, os, oa);
  }
}

__global__ __launch_bounds__(NTHR) void decode_kernel_f32(
    const float* enc, const float* emb, const float* Wih, const float* Whh,
    const float* bl, const float* Wpred, const float* bp, const float* Wjoin,
    const float* bj, const int* phon, float* out, float* wsf) {
  extern __shared__ float sm[];
  Ctx C;
  C.enc = enc; C.emb = emb; C.Wih = Wih; C.Whh = Whh; C.bl = bl;
  C.Wpred = Wpred; C.bp = bp; C.Wjoin = Wjoin; C.bj = bj; C.phon = phon;
  C.flags = (unsigned*)wsf;
  C.hx = (unsigned long long*)(wsf + WSF_HX);
  C.hhist = wsf + WSF_HHIST;
  C.preds = wsf + WSF_PREDS;
  C.pmax = wsf + F_PMAX;
  C.psum = wsf + F_PSUM;
  C.parg = (int*)(wsf + F_PARG);
  C.lse = wsf + F_LSE;
  C.out_align = out;
  C.out_pred  = out + (size_t)TT * VD;
  C.out_valid = out + (size_t)TT * VD + TT;

  const int tid = threadIdx.x;
  const int wid = tid >> 6, lane = tid & 63;
  unsigned ep = 1;

  chain_all_legacy(C, sm);
  heavy_barrier(C.flags);
  preds_gemm_legacy(C, sm);
  heavy_barrier(C.flags);

  int t = 0, tp = 0;
  while (t < TT && tp < NPH) {
    int K = CHUNK;
    if (TT - t < K) K = TT - t;
    if (NPH - tp < K) K = NPH - tp;
    joiner_gemm_f32(C, sm, t, K, tp);
    light_barrier(C.flags, ep);
    int* amax_l = (int*)(sm + S_AMAX);
    for (int j = wid; j < K; j += 8) {
      float m, s; int am;
      merge_row65(C, t + j, lane, m, s, am);
      if (lane == 0) {
        amax_l[j] = am;
        C.lse[t + j] = m + logf(s);
      }
    }
    __syncthreads();
    int cand = K;
    if (tid < K && amax_l[tid] == BLANK) cand = tid;
    #pragma unroll
    for (int msk = 32; msk; msk >>= 1) cand = min(cand, __shfl_xor(cand, msk, 64));
    int* red = (int*)(sm + S_RED);
    if (lane == 0) red[wid] = cand;
    __syncthreads();
    if (tid == 0) {
      int mn = red[0];
      for (int w2 = 1; w2 < 8; ++w2) mn = min(mn, red[w2]);
      red[8] = mn;
    }
    __syncthreads();
    int jb = red[8];
    __syncthreads();
    int nacc = (jb < K) ? jb + 1 : K;
    int nadv = (jb < K) ? jb : K;
    if (blockIdx.x == 0) {
      int* tok_sm = (int*)(sm + S_TOK);
      for (int j = tid; j < nacc; j += NTHR) {
        C.out_pred[t + j] = (j == jb) ? (float)BLANK : (float)tok_sm[tp + j + 2];
        C.out_valid[t + j] = 1.f;
      }
    }
    t += nacc; tp += nadv;
    if (jb < K) heavy_barrier(C.flags);
  }
  if (t < TT) {
    int Kt = TT - t;
    joiner_gemm_f32(C, sm, t, Kt, -1);
    light_barrier(C.flags, ep);
    for (int i = blockIdx.x * 8 + wid; i < Kt; i += NWG * 8) {
      float m, s; int am;
      merge_row65(C, t + i, lane, m, s, am);
      if (lane == 0) C.lse[t + i] = m + logf(s);
    }
    const int gtid = blockIdx.x * NTHR + tid;
    for (int i = gtid; i < Kt; i += NWG * NTHR) {
      C.out_pred[t + i] = (float)BLANK;
      C.out_valid[t + i] = 0.f;
    }
  }
  heavy_barrier(C.flags);
  for (int row = blockIdx.x; row < TT; row += NWG) {
    float l = C.lse[row];
    float* p = C.out_align + (size_t)row * VD;
    for (int i = tid; i < VD; i += NTHR) p[i] -= l;
  }
}

// ======================= host =======================

extern "C" void kernel_launch(void* const* d_in, const int* in_sizes, int n_in,
                              void* d_out, int out_size, void* d_ws, size_t ws_size,
                              hipStream_t stream) {
  const float* enc   = (const float*)d_in[0];
  const float* emb   = (const float*)d_in[1];
  const float* Wih   = (const float*)d_in[2];
  const float* Whh   = (const float*)d_in[3];
  const float* bl    = (const float*)d_in[4];
  const float* Wpred = (const float*)d_in[5];
  const float* bp    = (const float*)d_in[6];
  const float* Wjoin = (const float*)d_in[7];
  const float* bj    = (const float*)d_in[8];
  const int*   phon  = (const int*)d_in[9];
  float* out = (float*)d_out;
  float* wsf = (float*)d_ws;

  // flags + tagged h-exchange must start clean every call
  hipMemsetAsync(d_ws, 0, MEMSET_BYTES, stream);

  if (ws_size >= NEED_MFMA) {
    hipFuncSetAttribute((const void*)chain_kernel,
                        hipFuncAttributeMaxDynamicSharedMemorySize, CHAIN_SMEM);
    hipFuncSetAttribute((const void*)joinspec_kernel,
                        hipFuncAttributeMaxDynamicSharedMemorySize, JOIN_SMEM);
    hipFuncSetAttribute((const void*)decode_coop,
                        hipFuncAttributeMaxDynamicSharedMemorySize, JOIN_SMEM);
    hipFuncSetAttribute((const void*)jointail_kernel,
                        hipFuncAttributeMaxDynamicSharedMemorySize, JOIN_SMEM);

    wconv_kernel<<<1024, 512, 0, stream>>>(Wjoin, wsf);
    gx_kernel<<<416, 512, GEMM_SMEM, stream>>>(Wih, emb, bl, phon, wsf);
    {
      const float* WhhA = Whh; float* wsfA = wsf;
      void* a2[] = { &WhhA, &wsfA };
      hipError_t e = hipLaunchCooperativeKernel((void*)chain_kernel, dim3(256), dim3(NTHR),
                                                a2, CHAIN_SMEM, stream);
      if (e != hipSuccess)
        chain_kernel<<<dim3(256), dim3(NTHR), CHAIN_SMEM, stream>>>(Whh, wsf);
    }
    preds_kernel<<<104, 512, GEMM_SMEM, stream>>>(Wpred, bp, wsf);
    xspec_kernel<<<1024, 256, 0, stream>>>(enc, wsf);
    joinspec_kernel<<<455, NTHR, JOIN_SMEM, stream>>>(bj, out, wsf);
    {
      const float* encA = enc; const float* bjA = bj; const int* phonA = phon;
      float* outA = out; float* wsfA = wsf;
      void* a3[] = { &encA, &bjA, &phonA, &outA, &wsfA };
      hipError_t e = hipLaunchCooperativeKernel((void*)decode_coop, dim3(NWG), dim3(NTHR),
                                                a3, JOIN_SMEM, stream);
      if (e != hipSuccess)
        decode_coop<<<dim3(NWG), dim3(NTHR), JOIN_SMEM, stream>>>(enc, bj, phon, out, wsf);
    }
    jointail_kernel<<<1664, NTHR, JOIN_SMEM, stream>>>(bj, out, wsf);
    mergetail_kernel<<<256, NTHR, 0, stream>>>(out, wsf);
    sub_kernel<<<2048, 256, 0, stream>>>(out, wsf);
  } else {
    hipFuncSetAttribute((const void*)decode_kernel_f32,
                        hipFuncAttributeMaxDynamicSharedMemorySize, SMEM_BYTES_F32);
    void* args[] = { &enc, &emb, &Wih, &Whh, &bl, &Wpred, &bp, &Wjoin, &bj, &phon, &out, &wsf };
    hipError_t e = hipLaunchCooperativeKernel((void*)decode_kernel_f32, dim3(NWG), dim3(NTHR),
                                              args, SMEM_BYTES_F32, stream);
    if (e != hipSuccess) {
      decode_kernel_f32<<<dim3(NWG), dim3(NTHR), SMEM_BYTES_F32, stream>>>(
          enc, emb, Wih, Whh, bl, Wpred, bp, Wjoin, bj, phon, out, wsf);
    }
  }
}